// Round 3
// baseline (7151.799 us; speedup 1.0000x reference)
//
#include <hip/hip_runtime.h>
#include <hip/hip_cooperative_groups.h>
#include <math.h>

namespace cg = cooperative_groups;

#define VN 8192
#define DN 128
#define EN 262144
#define KD 512
#define KK (KD*KD)

// scalar slots
#define S_SS_LADJ 0
#define S_INV_C1  1
#define S_SS_S0   2
#define S_INV_C0  3
#define S_QRT_C0  4
#define S_SS_G    5
#define S_INV_CG  6
#define S_QRT_CG  7
#define S_TR_X    8
#define S_TR_S0   9
#define S_TR_YG   10

static __device__ __forceinline__ float waveReduceAdd(float v) {
#pragma unroll
  for (int o = 32; o; o >>= 1) v += __shfl_xor(v, o);
  return v;
}

// ---------- stage A: graph -> L_adj ----------

__global__ __launch_bounds__(256) void transpose_k(const float* __restrict__ in,
                                                   float* __restrict__ out) {
  __shared__ float s[32][33];
  int tx = threadIdx.x & 31, ty = threadIdx.x >> 5;
  int v0 = blockIdx.x * 32, k0 = blockIdx.y * 32;
  for (int r = ty; r < 32; r += 8) s[r][tx] = in[(size_t)(k0 + r) * VN + v0 + tx];
  __syncthreads();
  for (int r = ty; r < 32; r += 8) out[(size_t)(v0 + r) * KD + k0 + tx] = s[tx][r];
}

__global__ __launch_bounds__(256) void count_k(const float* __restrict__ x,
                                               const int* __restrict__ ei,
                                               int* __restrict__ ea, int* __restrict__ eb,
                                               float* __restrict__ ew,
                                               int* __restrict__ cnt,
                                               unsigned int* __restrict__ bitmap) {
  int e = (int)(((unsigned)blockIdx.x * 256u + threadIdx.x) >> 6);
  int lane = threadIdx.x & 63;
  if (e >= EN) return;
  int i = ei[e], j = ei[EN + e];
  int a = i < j ? i : j;
  int b = i < j ? j : i;
  int ok = 0;
  if (lane == 0) {
    if (i != j) {
      unsigned key = (unsigned)a * (unsigned)VN + (unsigned)b;
      unsigned m = 1u << (key & 31u);
      unsigned old = atomicOr(bitmap + (key >> 5), m);
      ok = (old & m) ? 0 : 1;
    }
  }
  ok = __shfl(ok, 0);
  if (!ok) { if (lane == 0) ea[e] = -1; return; }
  float d0 = x[a * DN + lane]      - x[b * DN + lane];
  float d1 = x[a * DN + 64 + lane] - x[b * DN + 64 + lane];
  float s = d0 * d0 + d1 * d1;
  s = waveReduceAdd(s);
  if (lane == 0) {
    ea[e] = a; eb[e] = b; ew[e] = expf(-s);
    atomicAdd(cnt + a, 1);
    atomicAdd(cnt + b, 1);
  }
}

__global__ __launch_bounds__(1024) void scan_k(const int* __restrict__ cnt,
                                               int* __restrict__ rowptr,
                                               int* __restrict__ cursor) {
  __shared__ int sd[1024];
  __shared__ int carry;
  int tid = threadIdx.x;
  if (tid == 0) { carry = 0; rowptr[0] = 0; }
  __syncthreads();
  for (int c = 0; c < VN / 1024; ++c) {
    int v = c * 1024 + tid;
    int xv = cnt[v];
    sd[tid] = xv;
    __syncthreads();
    for (int off = 1; off < 1024; off <<= 1) {
      int t = (tid >= off) ? sd[tid - off] : 0;
      __syncthreads();
      sd[tid] += t;
      __syncthreads();
    }
    int incl = sd[tid];
    int base = carry;
    rowptr[v + 1] = base + incl;
    cursor[v] = base + incl - xv;
    __syncthreads();
    if (tid == 1023) carry = base + incl;
    __syncthreads();
  }
}

__global__ __launch_bounds__(256) void fill_k(const int* __restrict__ ea, const int* __restrict__ eb,
                                              const float* __restrict__ ew,
                                              int* __restrict__ cursor,
                                              int* __restrict__ adjj, float* __restrict__ adjw) {
  int e = blockIdx.x * 256 + threadIdx.x;
  if (e >= EN) return;
  int a = ea[e];
  if (a < 0) return;
  int b = eb[e];
  float w = ew[e];
  int p = atomicAdd(cursor + a, 1); adjj[p] = b; adjw[p] = w;
  int q = atomicAdd(cursor + b, 1); adjj[q] = a; adjw[q] = w;
}

// k-sliced gather: slice (64 cols = 2 MB of pmatT) stays L2-resident.
__global__ __launch_bounds__(256) void buildB_k(const float* __restrict__ pmatT,
                                                const int* __restrict__ rowptr,
                                                const int* __restrict__ adjj,
                                                const float* __restrict__ adjw,
                                                float* __restrict__ Bout) {
  int v = blockIdx.x * 4 + (threadIdx.x >> 6);
  int lane = threadIdx.x & 63;
  int k = blockIdx.y * 64 + lane;
  int s = rowptr[v], e = rowptr[v + 1];
  float acc = 0.f, sw = 0.f;
  for (int p = s; p < e; ++p) {
    int jj = adjj[p];
    float w = adjw[p];
    acc += w * pmatT[(size_t)jj * KD + k];
    sw += w;
  }
  Bout[(size_t)v * KD + k] = sw * pmatT[(size_t)v * KD + k] - acc;
}

// C(512x512) += pmat(512x8192) @ B(8192x512), split-k over blockIdx.z
__global__ __launch_bounds__(256) void gemm_big_k(const float* __restrict__ A,
                                                  const float* __restrict__ B,
                                                  float* __restrict__ C) {
  __shared__ __align__(16) float As[32][34];
  __shared__ __align__(16) float Bs[32][34];
  int tid = threadIdx.x;
  int tx = tid & 15, ty = tid >> 4;
  int n0 = blockIdx.x * 32, m0 = blockIdx.y * 32;
  int kbase = blockIdx.z * (VN / 8);
  float a00 = 0.f, a01 = 0.f, a10 = 0.f, a11 = 0.f;
  for (int kt = kbase; kt < kbase + VN / 8; kt += 32) {
#pragma unroll
    for (int u = 0; u < 4; ++u) {
      int li = tid * 4 + u;
      int r = li >> 5, c = li & 31;
      As[c][r] = A[(size_t)(m0 + r) * VN + kt + c];
      Bs[r][c] = B[(size_t)(kt + r) * KD + n0 + c];
    }
    __syncthreads();
#pragma unroll
    for (int k = 0; k < 32; ++k) {
      float2 av = *(const float2*)&As[k][2 * ty];
      float2 bv = *(const float2*)&Bs[k][2 * tx];
      a00 += av.x * bv.x; a01 += av.x * bv.y;
      a10 += av.y * bv.x; a11 += av.y * bv.y;
    }
    __syncthreads();
  }
  int m = m0 + 2 * ty, n = n0 + 2 * tx;
  atomicAdd(&C[m * KD + n], a00);
  atomicAdd(&C[m * KD + n + 1], a01);
  atomicAdd(&C[(m + 1) * KD + n], a10);
  atomicAdd(&C[(m + 1) * KD + n + 1], a11);
}

// ---------- 512x512 GEMM tile body ----------

static __device__ __forceinline__ void gemm_body(const float* __restrict__ A,
                                                 const float* __restrict__ B,
                                                 const float* __restrict__ Dm,
                                                 float* __restrict__ C,
                                                 float alpha, float beta) {
  __shared__ __align__(16) float As[32][34];
  __shared__ __align__(16) float Bs[32][34];
  int tid = threadIdx.x;
  int tx = tid & 15, ty = tid >> 4;
  int n0 = blockIdx.x * 32, m0 = blockIdx.y * 32;
  float a00 = 0.f, a01 = 0.f, a10 = 0.f, a11 = 0.f;
  for (int kt = 0; kt < KD; kt += 32) {
#pragma unroll
    for (int u = 0; u < 4; ++u) {
      int li = tid * 4 + u;
      int r = li >> 5, c = li & 31;
      As[c][r] = A[(m0 + r) * KD + kt + c];
      Bs[r][c] = B[(kt + r) * KD + n0 + c];
    }
    __syncthreads();
#pragma unroll
    for (int k = 0; k < 32; ++k) {
      float2 av = *(const float2*)&As[k][2 * ty];
      float2 bv = *(const float2*)&Bs[k][2 * tx];
      a00 += av.x * bv.x; a01 += av.x * bv.y;
      a10 += av.y * bv.x; a11 += av.y * bv.y;
    }
    __syncthreads();
  }
  int m = m0 + 2 * ty, n = n0 + 2 * tx;
  float d00 = 0.f, d01 = 0.f, d10 = 0.f, d11 = 0.f;
  if (beta != 0.0f) {
    d00 = Dm[m * KD + n];       d01 = Dm[m * KD + n + 1];
    d10 = Dm[(m + 1) * KD + n]; d11 = Dm[(m + 1) * KD + n + 1];
  }
  C[m * KD + n]           = alpha * a00 + beta * d00;
  C[m * KD + n + 1]       = alpha * a01 + beta * d01;
  C[(m + 1) * KD + n]     = alpha * a10 + beta * d10;
  C[(m + 1) * KD + n + 1] = alpha * a11 + beta * d11;
}

__global__ __launch_bounds__(256) void gemm_kk(const float* __restrict__ A,
                                               const float* __restrict__ B,
                                               const float* __restrict__ Dm,
                                               float* __restrict__ C,
                                               float alpha, float beta) {
  gemm_body(A, B, Dm, C, alpha, beta);
}

// two independent GEMMs in one launch (blockIdx.z picks); shared alpha, per-GEMM beta
__global__ __launch_bounds__(256) void gemm_dual(const float* A0, const float* B0,
                                                 const float* D0, float* C0,
                                                 const float* A1, const float* B1,
                                                 const float* D1, float* C1,
                                                 float alpha, float beta0, float beta1) {
  if (blockIdx.z == 0) gemm_body(A0, B0, D0, C0, alpha, beta0);
  else                 gemm_body(A1, B1, D1, C1, alpha, beta1);
}

// ---------- cooperative fused NS loops ----------

// inverse, residual form: X' = X + X*R ; R' = R*R   (1 grid-sync / iter)
__global__ __launch_bounds__(256) void inv_loop_k(float* Xa, float* Xb,
                                                  float* Ra, float* Rb, int iters) {
  cg::grid_group grid = cg::this_grid();
  for (int it = 0; it < iters; ++it) {
    gemm_body(Xa, Ra, Xa, Xb, 1.0f, 1.0f);
    gemm_body(Ra, Ra, nullptr, Rb, 1.0f, 0.0f);
    grid.sync();
    float* t = Xa; Xa = Xb; Xb = t;
    t = Ra; Ra = Rb; Rb = t;
  }
}

// coupled sqrt: P = Z*Y ; Y' = 1.5Y - 0.5*Y*P ; Z' = 1.5Z - 0.5*P*Z
__global__ __launch_bounds__(256) void sqrt_loop_k(float* Ya, float* Yb,
                                                   float* Za, float* Zb,
                                                   float* Pm, int iters) {
  cg::grid_group grid = cg::this_grid();
  for (int it = 0; it < iters; ++it) {
    gemm_body(Za, Ya, nullptr, Pm, 1.0f, 0.0f);
    grid.sync();
    gemm_body(Ya, Pm, Ya, Yb, -0.5f, 1.5f);
    gemm_body(Pm, Za, Za, Zb, -0.5f, 1.5f);
    grid.sync();
    float* t = Ya; Ya = Yb; Yb = t;
    t = Za; Za = Zb; Zb = t;
  }
}

// ---------- small utility kernels ----------

__global__ __launch_bounds__(256) void sumsq_k(const float* __restrict__ A, int n,
                                               float* __restrict__ slot) {
  float s = 0.f;
  for (int i = blockIdx.x * 256 + threadIdx.x; i < n; i += gridDim.x * 256) {
    float v = A[i];
    s += v * v;
  }
  __shared__ float p[4];
  s = waveReduceAdd(s);
  if ((threadIdx.x & 63) == 0) p[threadIdx.x >> 6] = s;
  __syncthreads();
  if (threadIdx.x == 0) atomicAdd(slot, p[0] + p[1] + p[2] + p[3]);
}

__global__ __launch_bounds__(512) void trace_k(const float* __restrict__ A,
                                               float* __restrict__ slot) {
  float v = A[(size_t)threadIdx.x * KD + threadIdx.x];
  __shared__ float p[8];
  v = waveReduceAdd(v);
  if ((threadIdx.x & 63) == 0) p[threadIdx.x >> 6] = v;
  __syncthreads();
  if (threadIdx.x == 0) {
    float t = 0.f;
    for (int i = 0; i < 8; ++i) t += p[i];
    slot[0] = t;
  }
}

__global__ void derive_k(const float* __restrict__ in, float* __restrict__ o_rsqrt,
                         float* __restrict__ o_qroot) {
  float x = in[0];
  o_rsqrt[0] = 1.0f / sqrtf(x);
  if (o_qroot) o_qroot[0] = powf(x, 0.25f);
}

// X0 = c*I ; R0 = I - c*A
__global__ __launch_bounds__(256) void initinv_k(const float* __restrict__ A,
                                                 const float* __restrict__ s,
                                                 float* __restrict__ X0,
                                                 float* __restrict__ R0) {
  int idx = blockIdx.x * 256 + threadIdx.x;
  if (idx >= KK) return;
  int r = idx >> 9, c = idx & (KD - 1);
  float cv = s[0];
  float id = (r == c) ? 1.0f : 0.0f;
  X0[idx] = id * cv;
  R0[idx] = id - cv * A[idx];
}

__global__ __launch_bounds__(256) void setid_const_k(float* __restrict__ C, float val) {
  int idx = blockIdx.x * 256 + threadIdx.x;
  if (idx >= KK) return;
  int r = idx >> 9, c = idx & (KD - 1);
  C[idx] = (r == c) ? val : 0.0f;
}

__global__ __launch_bounds__(256) void scale_k(const float* __restrict__ A,
                                               const float* __restrict__ s,
                                               float* __restrict__ C) {
  int idx = blockIdx.x * 256 + threadIdx.x;
  if (idx >= KK) return;
  C[idx] = A[idx] * s[0];
}

__global__ __launch_bounds__(256) void sym_k(const float* __restrict__ G,
                                             float* __restrict__ Out) {
  int idx = blockIdx.x * 256 + threadIdx.x;
  if (idx >= KK) return;
  int r = idx >> 9, c = idx & (KD - 1);
  Out[idx] = 0.5f * (G[idx] + G[c * KD + r]);
}

__global__ void final_k(const float* __restrict__ scal, float* __restrict__ out) {
  out[0] = scal[S_TR_X] + scal[S_TR_S0] - 2.0f * scal[S_QRT_CG] * scal[S_TR_YG];
}

// ---------- host helpers: cooperative with non-coop fallback ----------

static void run_inv(hipStream_t stream, float* Xa, float* Xb, float* Ra, float* Rb,
                    int iters) {
  void* args[] = {&Xa, &Xb, &Ra, &Rb, &iters};
  hipError_t err = hipLaunchCooperativeKernel((const void*)inv_loop_k, dim3(16, 16),
                                              dim3(256), args, 0, stream);
  if (err == hipSuccess) return;
  // fallback: same math, one dual launch per iteration
  for (int it = 0; it < iters; ++it) {
    gemm_dual<<<dim3(16, 16, 2), 256, 0, stream>>>(Xa, Ra, Xa, Xb,
                                                   Ra, Ra, nullptr, Rb,
                                                   1.0f, 1.0f, 0.0f);
    float* t = Xa; Xa = Xb; Xb = t;
    t = Ra; Ra = Rb; Rb = t;
  }
}

static void run_sqrt(hipStream_t stream, float* Ya, float* Yb, float* Za, float* Zb,
                     float* Pm, int iters) {
  void* args[] = {&Ya, &Yb, &Za, &Zb, &Pm, &iters};
  hipError_t err = hipLaunchCooperativeKernel((const void*)sqrt_loop_k, dim3(16, 16),
                                              dim3(256), args, 0, stream);
  if (err == hipSuccess) return;
  for (int it = 0; it < iters; ++it) {
    gemm_kk<<<dim3(16, 16), 256, 0, stream>>>(Za, Ya, nullptr, Pm, 1.0f, 0.0f);
    gemm_dual<<<dim3(16, 16, 2), 256, 0, stream>>>(Ya, Pm, Ya, Yb,
                                                   Pm, Za, Za, Zb,
                                                   -0.5f, 1.5f, 1.5f);
    float* t = Ya; Ya = Yb; Yb = t;
    t = Za; Za = Zb; Zb = t;
  }
}

// ---------- host ----------

extern "C" void kernel_launch(void* const* d_in, const int* in_sizes, int n_in,
                              void* d_out, int out_size, void* d_ws, size_t ws_size,
                              hipStream_t stream) {
  (void)in_sizes; (void)n_in; (void)out_size; (void)ws_size;
  const float* x    = (const float*)d_in[0];  // V x D
  const float* S0   = (const float*)d_in[1];  // K x K
  const int*   ei   = (const int*)d_in[2];    // 2 x E
  const float* pmat = (const float*)d_in[3];  // K x V
  float* out = (float*)d_out;
  char* ws = (char*)d_ws;

  size_t off = 0;
  unsigned* bitmap = (unsigned*)(ws + off); off += (size_t)VN * VN / 8;       // 8 MB
  size_t off_pool = off;                                                      // pool overlays pmatT
  float* pmatT = (float*)(ws + off); off += (size_t)VN * KD * 4;              // 16 MB
  float* Bm    = (float*)(ws + off); off += (size_t)VN * KD * 4;              // 16 MB
  int*   ea    = (int*)(ws + off);   off += (size_t)EN * 4;
  int*   eb    = (int*)(ws + off);   off += (size_t)EN * 4;
  float* ew    = (float*)(ws + off); off += (size_t)EN * 4;
  int*   cnt   = (int*)(ws + off);   off += (size_t)VN * 4;
  int*  rowptr = (int*)(ws + off);   off += (size_t)(VN + 2) * 4;
  int*  cursor = (int*)(ws + off);   off += (size_t)VN * 4;
  int*   adjj  = (int*)(ws + off);   off += (size_t)2 * EN * 4;
  float* adjw  = (float*)(ws + off); off += (size_t)2 * EN * 4;
  float* scal  = (float*)(ws + off); off += 64 * 4;

  // K x K pool (13 MB) overlays pmatT region (16 MB); pmatT dead before first pool write
  float* P[13];
  for (int i = 0; i < 13; ++i) P[i] = (float*)(ws + off_pool + (size_t)i * KK * 4);
  float* Ladj = P[0];
  float* Xa = P[1]; float* Xb = P[2]; float* Ra = P[3]; float* Rb = P[4];
  float* Ya = P[5]; float* Yb = P[6]; float* Za = P[7]; float* Zb = P[8];
  float* Pm = P[9]; float* S0h = P[10]; float* TMP = P[11]; float* G = P[12];

  hipMemsetAsync(bitmap, 0, (size_t)VN * VN / 8, stream);
  hipMemsetAsync(cnt, 0, (size_t)VN * 4, stream);
  hipMemsetAsync(scal, 0, 64 * 4, stream);

  // stage A: graph construction -> L_adj
  transpose_k<<<dim3(VN / 32, KD / 32), 256, 0, stream>>>(pmat, pmatT);
  count_k<<<EN / 4, 256, 0, stream>>>(x, ei, ea, eb, ew, cnt, bitmap);
  scan_k<<<1, 1024, 0, stream>>>(cnt, rowptr, cursor);
  fill_k<<<EN / 256, 256, 0, stream>>>(ea, eb, ew, cursor, adjj, adjw);
  buildB_k<<<dim3(VN / 4, KD / 64), 256, 0, stream>>>(pmatT, rowptr, adjj, adjw, Bm);
  setid_const_k<<<KK / 256, 256, 0, stream>>>(Ladj, 1e-5f);
  gemm_big_k<<<dim3(16, 16, 8), 256, 0, stream>>>(pmat, Bm, Ladj);

  // stage B: S1 = inv(L_adj) via residual-form Newton-Schulz
  sumsq_k<<<256, 256, 0, stream>>>(Ladj, KK, &scal[S_SS_LADJ]);
  derive_k<<<1, 1, 0, stream>>>(&scal[S_SS_LADJ], &scal[S_INV_C1], nullptr);
  initinv_k<<<KK / 256, 256, 0, stream>>>(Ladj, &scal[S_INV_C1], Xa, Ra);
  run_inv(stream, Xa, Xb, Ra, Rb, 24);  // even -> result in Xa
  trace_k<<<1, 512, 0, stream>>>(Xa, &scal[S_TR_X]);

  // stage C: S0_sqrt via coupled Newton-Schulz
  sumsq_k<<<256, 256, 0, stream>>>(S0, KK, &scal[S_SS_S0]);
  derive_k<<<1, 1, 0, stream>>>(&scal[S_SS_S0], &scal[S_INV_C0], &scal[S_QRT_C0]);
  scale_k<<<KK / 256, 256, 0, stream>>>(S0, &scal[S_INV_C0], Ya);
  setid_const_k<<<KK / 256, 256, 0, stream>>>(Za, 1.0f);
  run_sqrt(stream, Ya, Yb, Za, Zb, Pm, 18);  // even -> result in Ya
  scale_k<<<KK / 256, 256, 0, stream>>>(Ya, &scal[S_QRT_C0], S0h);
  trace_k<<<1, 512, 0, stream>>>(S0, &scal[S_TR_S0]);

  // stage D: G = S0h @ S1 @ S0h, then tr(sqrtm(G))
  gemm_kk<<<dim3(16, 16), 256, 0, stream>>>(S0h, Xa, nullptr, TMP, 1.0f, 0.0f);
  gemm_kk<<<dim3(16, 16), 256, 0, stream>>>(TMP, S0h, nullptr, G, 1.0f, 0.0f);
  sym_k<<<KK / 256, 256, 0, stream>>>(G, TMP);
  sumsq_k<<<256, 256, 0, stream>>>(TMP, KK, &scal[S_SS_G]);
  derive_k<<<1, 1, 0, stream>>>(&scal[S_SS_G], &scal[S_INV_CG], &scal[S_QRT_CG]);
  scale_k<<<KK / 256, 256, 0, stream>>>(TMP, &scal[S_INV_CG], Ya);
  setid_const_k<<<KK / 256, 256, 0, stream>>>(Za, 1.0f);
  run_sqrt(stream, Ya, Yb, Za, Zb, Pm, 26);  // even -> result in Ya
  trace_k<<<1, 512, 0, stream>>>(Ya, &scal[S_TR_YG]);

  final_k<<<1, 1, 0, stream>>>(scal, out);
}

// Round 5
// 3430.944 us; speedup vs baseline: 2.0845x; 2.0845x over previous
//
#include <hip/hip_runtime.h>
#include <math.h>

#define VN 8192
#define DN 128
#define EN 262144
#define KD 512
#define KK (KD*KD)

// scalar slots
#define S_SS_LADJ 0
#define S_INV_C1  1
#define S_SS_S0   2
#define S_INV_C0  3
#define S_QRT_C0  4
#define S_SS_G    5
#define S_INV_CG  6
#define S_QRT_CG  7
#define S_TR_X    8
#define S_TR_S0   9
#define S_TR_YG   10

static __device__ __forceinline__ float waveReduceAdd(float v) {
#pragma unroll
  for (int o = 32; o; o >>= 1) v += __shfl_xor(v, o);
  return v;
}

// ---------- stage A: graph -> L_adj ----------

__global__ __launch_bounds__(256) void transpose_k(const float* __restrict__ in,
                                                   float* __restrict__ out) {
  __shared__ float s[32][33];
  int tx = threadIdx.x & 31, ty = threadIdx.x >> 5;
  int v0 = blockIdx.x * 32, k0 = blockIdx.y * 32;
  for (int r = ty; r < 32; r += 8) s[r][tx] = in[(size_t)(k0 + r) * VN + v0 + tx];
  __syncthreads();
  for (int r = ty; r < 32; r += 8) out[(size_t)(v0 + r) * KD + k0 + tx] = s[tx][r];
}

__global__ __launch_bounds__(256) void count_k(const float* __restrict__ x,
                                               const int* __restrict__ ei,
                                               int* __restrict__ ea, int* __restrict__ eb,
                                               float* __restrict__ ew,
                                               int* __restrict__ cnt,
                                               unsigned int* __restrict__ bitmap) {
  int e = (int)(((unsigned)blockIdx.x * 256u + threadIdx.x) >> 6);
  int lane = threadIdx.x & 63;
  if (e >= EN) return;
  int i = ei[e], j = ei[EN + e];
  int a = i < j ? i : j;
  int b = i < j ? j : i;
  int ok = 0;
  if (lane == 0) {
    if (i != j) {
      unsigned key = (unsigned)a * (unsigned)VN + (unsigned)b;
      unsigned m = 1u << (key & 31u);
      unsigned old = atomicOr(bitmap + (key >> 5), m);
      ok = (old & m) ? 0 : 1;
    }
  }
  ok = __shfl(ok, 0);
  if (!ok) { if (lane == 0) ea[e] = -1; return; }
  float d0 = x[a * DN + lane]      - x[b * DN + lane];
  float d1 = x[a * DN + 64 + lane] - x[b * DN + 64 + lane];
  float s = d0 * d0 + d1 * d1;
  s = waveReduceAdd(s);
  if (lane == 0) {
    ea[e] = a; eb[e] = b; ew[e] = expf(-s);
    atomicAdd(cnt + a, 1);
    atomicAdd(cnt + b, 1);
  }
}

__global__ __launch_bounds__(1024) void scan_k(const int* __restrict__ cnt,
                                               int* __restrict__ rowptr,
                                               int* __restrict__ cursor) {
  __shared__ int sd[1024];
  __shared__ int carry;
  int tid = threadIdx.x;
  if (tid == 0) { carry = 0; rowptr[0] = 0; }
  __syncthreads();
  for (int c = 0; c < VN / 1024; ++c) {
    int v = c * 1024 + tid;
    int xv = cnt[v];
    sd[tid] = xv;
    __syncthreads();
    for (int off = 1; off < 1024; off <<= 1) {
      int t = (tid >= off) ? sd[tid - off] : 0;
      __syncthreads();
      sd[tid] += t;
      __syncthreads();
    }
    int incl = sd[tid];
    int base = carry;
    rowptr[v + 1] = base + incl;
    cursor[v] = base + incl - xv;
    __syncthreads();
    if (tid == 1023) carry = base + incl;
    __syncthreads();
  }
}

__global__ __launch_bounds__(256) void fill_k(const int* __restrict__ ea, const int* __restrict__ eb,
                                              const float* __restrict__ ew,
                                              int* __restrict__ cursor,
                                              int* __restrict__ adjj, float* __restrict__ adjw) {
  int e = blockIdx.x * 256 + threadIdx.x;
  if (e >= EN) return;
  int a = ea[e];
  if (a < 0) return;
  int b = eb[e];
  float w = ew[e];
  int p = atomicAdd(cursor + a, 1); adjj[p] = b; adjw[p] = w;
  int q = atomicAdd(cursor + b, 1); adjj[q] = a; adjw[q] = w;
}

// k-sliced gather: slice (64 cols = 2 MB of pmatT) stays L2-resident.
__global__ __launch_bounds__(256) void buildB_k(const float* __restrict__ pmatT,
                                                const int* __restrict__ rowptr,
                                                const int* __restrict__ adjj,
                                                const float* __restrict__ adjw,
                                                float* __restrict__ Bout) {
  int v = blockIdx.x * 4 + (threadIdx.x >> 6);
  int lane = threadIdx.x & 63;
  int k = blockIdx.y * 64 + lane;
  int s = rowptr[v], e = rowptr[v + 1];
  float acc = 0.f, sw = 0.f;
  for (int p = s; p < e; ++p) {
    int jj = adjj[p];
    float w = adjw[p];
    acc += w * pmatT[(size_t)jj * KD + k];
    sw += w;
  }
  Bout[(size_t)v * KD + k] = sw * pmatT[(size_t)v * KD + k] - acc;
}

// C(512x512) += pmat(512x8192) @ B(8192x512), split-k over blockIdx.z
__global__ __launch_bounds__(256) void gemm_big_k(const float* __restrict__ A,
                                                  const float* __restrict__ B,
                                                  float* __restrict__ C) {
  __shared__ __align__(16) float As[32][34];
  __shared__ __align__(16) float Bs[32][34];
  int tid = threadIdx.x;
  int tx = tid & 15, ty = tid >> 4;
  int n0 = blockIdx.x * 32, m0 = blockIdx.y * 32;
  int kbase = blockIdx.z * (VN / 8);
  float a00 = 0.f, a01 = 0.f, a10 = 0.f, a11 = 0.f;
  for (int kt = kbase; kt < kbase + VN / 8; kt += 32) {
#pragma unroll
    for (int u = 0; u < 4; ++u) {
      int li = tid * 4 + u;
      int r = li >> 5, c = li & 31;
      As[c][r] = A[(size_t)(m0 + r) * VN + kt + c];
      Bs[r][c] = B[(size_t)(kt + r) * KD + n0 + c];
    }
    __syncthreads();
#pragma unroll
    for (int k = 0; k < 32; ++k) {
      float2 av = *(const float2*)&As[k][2 * ty];
      float2 bv = *(const float2*)&Bs[k][2 * tx];
      a00 += av.x * bv.x; a01 += av.x * bv.y;
      a10 += av.y * bv.x; a11 += av.y * bv.y;
    }
    __syncthreads();
  }
  int m = m0 + 2 * ty, n = n0 + 2 * tx;
  atomicAdd(&C[m * KD + n], a00);
  atomicAdd(&C[m * KD + n + 1], a01);
  atomicAdd(&C[(m + 1) * KD + n], a10);
  atomicAdd(&C[(m + 1) * KD + n + 1], a11);
}

// ---------- generic K x K GEMM tile body ----------
// C = alpha * (A+A2) @ (B+B2) + beta * Dm, over K-range [k0, k0+klen)

static __device__ __forceinline__ void gemm_body_gen(
    const float* __restrict__ A, const float* __restrict__ A2,
    const float* __restrict__ B, const float* __restrict__ B2,
    const float* __restrict__ Dm, float* __restrict__ C,
    float alpha, float beta, int k0, int klen) {
  __shared__ __align__(16) float As[32][34];
  __shared__ __align__(16) float Bs[32][34];
  int tid = threadIdx.x;
  int tx = tid & 15, ty = tid >> 4;
  int n0 = blockIdx.x * 32, m0 = blockIdx.y * 32;
  float a00 = 0.f, a01 = 0.f, a10 = 0.f, a11 = 0.f;
  for (int kt = k0; kt < k0 + klen; kt += 32) {
#pragma unroll
    for (int u = 0; u < 4; ++u) {
      int li = tid * 4 + u;
      int r = li >> 5, c = li & 31;
      float av = A[(m0 + r) * KD + kt + c];
      if (A2) av += A2[(m0 + r) * KD + kt + c];
      As[c][r] = av;
      float bv = B[(kt + r) * KD + n0 + c];
      if (B2) bv += B2[(kt + r) * KD + n0 + c];
      Bs[r][c] = bv;
    }
    __syncthreads();
#pragma unroll
    for (int k = 0; k < 32; ++k) {
      float2 av = *(const float2*)&As[k][2 * ty];
      float2 bv = *(const float2*)&Bs[k][2 * tx];
      a00 += av.x * bv.x; a01 += av.x * bv.y;
      a10 += av.y * bv.x; a11 += av.y * bv.y;
    }
    __syncthreads();
  }
  int m = m0 + 2 * ty, n = n0 + 2 * tx;
  float d00 = 0.f, d01 = 0.f, d10 = 0.f, d11 = 0.f;
  if (beta != 0.0f) {
    d00 = Dm[m * KD + n];       d01 = Dm[m * KD + n + 1];
    d10 = Dm[(m + 1) * KD + n]; d11 = Dm[(m + 1) * KD + n + 1];
  }
  C[m * KD + n]           = alpha * a00 + beta * d00;
  C[m * KD + n + 1]       = alpha * a01 + beta * d01;
  C[(m + 1) * KD + n]     = alpha * a10 + beta * d10;
  C[(m + 1) * KD + n + 1] = alpha * a11 + beta * d11;
}

__global__ __launch_bounds__(256) void gemm_kk(const float* __restrict__ A,
                                               const float* __restrict__ B,
                                               const float* __restrict__ Dm,
                                               float* __restrict__ C,
                                               float alpha, float beta) {
  gemm_body_gen(A, nullptr, B, nullptr, Dm, C, alpha, beta, 0, KD);
}

// stage B+C combined launch A: z0/z1 = split-K halves of Pm = Za@Ya;
// z2 = Xb = Xa@Ra + Xa; z3 = Rb = Ra@Ra.   (1024 blocks -> 4 blocks/CU)
__global__ __launch_bounds__(256) void bcA_k(const float* Za, const float* Ya,
                                             float* Pm0, float* Pm1,
                                             const float* Xa, const float* Ra,
                                             float* Xb, float* Rb) {
  int z = blockIdx.z;
  if (z == 0)      gemm_body_gen(Za, nullptr, Ya, nullptr, nullptr, Pm0, 1.f, 0.f, 0, KD / 2);
  else if (z == 1) gemm_body_gen(Za, nullptr, Ya, nullptr, nullptr, Pm1, 1.f, 0.f, KD / 2, KD / 2);
  else if (z == 2) gemm_body_gen(Xa, nullptr, Ra, nullptr, Xa, Xb, 1.f, 1.f, 0, KD);
  else             gemm_body_gen(Ra, nullptr, Ra, nullptr, nullptr, Rb, 1.f, 0.f, 0, KD);
}

// sqrt phase 2: Yb = 1.5*Ya - 0.5*Ya@(Pm0+Pm1); Zb = 1.5*Za - 0.5*(Pm0+Pm1)@Za
__global__ __launch_bounds__(256) void yz_k(const float* Ya, const float* Za,
                                            const float* Pm0, const float* Pm1,
                                            float* Yb, float* Zb) {
  if (blockIdx.z == 0) gemm_body_gen(Ya, nullptr, Pm0, Pm1, Ya, Yb, -0.5f, 1.5f, 0, KD);
  else                 gemm_body_gen(Pm0, Pm1, Za, nullptr, Za, Zb, -0.5f, 1.5f, 0, KD);
}

// inverse-only dual: Xb = Xa@Ra + Xa ; Rb = Ra@Ra
__global__ __launch_bounds__(256) void invduo_k(const float* Xa, const float* Ra,
                                                float* Xb, float* Rb) {
  if (blockIdx.z == 0) gemm_body_gen(Xa, nullptr, Ra, nullptr, Xa, Xb, 1.f, 1.f, 0, KD);
  else                 gemm_body_gen(Ra, nullptr, Ra, nullptr, nullptr, Rb, 1.f, 0.f, 0, KD);
}

// sqrt phase 1 alone (stage D): split-K halves of Pm = Za@Ya
__global__ __launch_bounds__(256) void pm_k(const float* Za, const float* Ya,
                                            float* Pm0, float* Pm1) {
  if (blockIdx.z == 0) gemm_body_gen(Za, nullptr, Ya, nullptr, nullptr, Pm0, 1.f, 0.f, 0, KD / 2);
  else                 gemm_body_gen(Za, nullptr, Ya, nullptr, nullptr, Pm1, 1.f, 0.f, KD / 2, KD / 2);
}

// ---------- small utility kernels ----------

__global__ __launch_bounds__(256) void sumsq_k(const float* __restrict__ A, int n,
                                               float* __restrict__ slot) {
  float s = 0.f;
  for (int i = blockIdx.x * 256 + threadIdx.x; i < n; i += gridDim.x * 256) {
    float v = A[i];
    s += v * v;
  }
  __shared__ float p[4];
  s = waveReduceAdd(s);
  if ((threadIdx.x & 63) == 0) p[threadIdx.x >> 6] = s;
  __syncthreads();
  if (threadIdx.x == 0) atomicAdd(slot, p[0] + p[1] + p[2] + p[3]);
}

__global__ __launch_bounds__(512) void trace_k(const float* __restrict__ A,
                                               float* __restrict__ slot) {
  float v = A[(size_t)threadIdx.x * KD + threadIdx.x];
  __shared__ float p[8];
  v = waveReduceAdd(v);
  if ((threadIdx.x & 63) == 0) p[threadIdx.x >> 6] = v;
  __syncthreads();
  if (threadIdx.x == 0) {
    float t = 0.f;
    for (int i = 0; i < 8; ++i) t += p[i];
    slot[0] = t;
  }
}

__global__ void derive_k(const float* __restrict__ in, float* __restrict__ o_rsqrt,
                         float* __restrict__ o_qroot) {
  float x = in[0];
  o_rsqrt[0] = 1.0f / sqrtf(x);
  if (o_qroot) o_qroot[0] = powf(x, 0.25f);
}

// X0 = c*I ; R0 = I - c*A
__global__ __launch_bounds__(256) void initinv_k(const float* __restrict__ A,
                                                 const float* __restrict__ s,
                                                 float* __restrict__ X0,
                                                 float* __restrict__ R0) {
  int idx = blockIdx.x * 256 + threadIdx.x;
  if (idx >= KK) return;
  int r = idx >> 9, c = idx & (KD - 1);
  float cv = s[0];
  float id = (r == c) ? 1.0f : 0.0f;
  X0[idx] = id * cv;
  R0[idx] = id - cv * A[idx];
}

__global__ __launch_bounds__(256) void setid_const_k(float* __restrict__ C, float val) {
  int idx = blockIdx.x * 256 + threadIdx.x;
  if (idx >= KK) return;
  int r = idx >> 9, c = idx & (KD - 1);
  C[idx] = (r == c) ? val : 0.0f;
}

__global__ __launch_bounds__(256) void scale_k(const float* __restrict__ A,
                                               const float* __restrict__ s,
                                               float* __restrict__ C) {
  int idx = blockIdx.x * 256 + threadIdx.x;
  if (idx >= KK) return;
  C[idx] = A[idx] * s[0];
}

__global__ __launch_bounds__(256) void sym_k(const float* __restrict__ G,
                                             float* __restrict__ Out) {
  int idx = blockIdx.x * 256 + threadIdx.x;
  if (idx >= KK) return;
  int r = idx >> 9, c = idx & (KD - 1);
  Out[idx] = 0.5f * (G[idx] + G[c * KD + r]);
}

__global__ void final_k(const float* __restrict__ scal, float* __restrict__ out) {
  out[0] = scal[S_TR_X] + scal[S_TR_S0] - 2.0f * scal[S_QRT_CG] * scal[S_TR_YG];
}

// ---------- host ----------

extern "C" void kernel_launch(void* const* d_in, const int* in_sizes, int n_in,
                              void* d_out, int out_size, void* d_ws, size_t ws_size,
                              hipStream_t stream) {
  (void)in_sizes; (void)n_in; (void)out_size; (void)ws_size;
  const float* x    = (const float*)d_in[0];  // V x D
  const float* S0   = (const float*)d_in[1];  // K x K
  const int*   ei   = (const int*)d_in[2];    // 2 x E
  const float* pmat = (const float*)d_in[3];  // K x V
  float* out = (float*)d_out;
  char* ws = (char*)d_ws;

  size_t off = 0;
  unsigned* bitmap = (unsigned*)(ws + off); off += (size_t)VN * VN / 8;       // 8 MB
  size_t off_pool = off;                                                      // pool overlays pmatT
  float* pmatT = (float*)(ws + off); off += (size_t)VN * KD * 4;              // 16 MB
  float* Bm    = (float*)(ws + off); off += (size_t)VN * KD * 4;              // 16 MB
  int*   ea    = (int*)(ws + off);   off += (size_t)EN * 4;
  int*   eb    = (int*)(ws + off);   off += (size_t)EN * 4;
  float* ew    = (float*)(ws + off); off += (size_t)EN * 4;
  int*   cnt   = (int*)(ws + off);   off += (size_t)VN * 4;
  int*  rowptr = (int*)(ws + off);   off += (size_t)(VN + 2) * 4;
  int*  cursor = (int*)(ws + off);   off += (size_t)VN * 4;
  int*   adjj  = (int*)(ws + off);   off += (size_t)2 * EN * 4;
  float* adjw  = (float*)(ws + off); off += (size_t)2 * EN * 4;
  float* scal  = (float*)(ws + off); off += 64 * 4;

  // K x K pool (14 x 1 MB = 14 MB) inside the dead pmatT region (16 MB).
  // pmatT is dead after buildB_k; pool first written by setid/gemm_big after that.
  float* P[14];
  for (int i = 0; i < 14; ++i) P[i] = (float*)(ws + off_pool + (size_t)i * KK * 4);
  float* Ladj = P[0];
  float* Xa = P[1]; float* Xb = P[2]; float* Ra = P[3]; float* Rb = P[4];
  float* Ya = P[5]; float* Yb = P[6]; float* Za = P[7]; float* Zb = P[8];
  float* Pm0 = P[9]; float* Pm1 = P[10];
  float* S0h = P[11]; float* TMP = P[12]; float* G = P[13];

  hipMemsetAsync(bitmap, 0, (size_t)VN * VN / 8, stream);
  hipMemsetAsync(cnt, 0, (size_t)VN * 4, stream);
  hipMemsetAsync(scal, 0, 64 * 4, stream);

  // stage A: graph construction -> L_adj
  transpose_k<<<dim3(VN / 32, KD / 32), 256, 0, stream>>>(pmat, pmatT);
  count_k<<<EN / 4, 256, 0, stream>>>(x, ei, ea, eb, ew, cnt, bitmap);
  scan_k<<<1, 1024, 0, stream>>>(cnt, rowptr, cursor);
  fill_k<<<EN / 256, 256, 0, stream>>>(ea, eb, ew, cursor, adjj, adjw);
  buildB_k<<<dim3(VN / 4, KD / 64), 256, 0, stream>>>(pmatT, rowptr, adjj, adjw, Bm);
  setid_const_k<<<KK / 256, 256, 0, stream>>>(Ladj, 1e-5f);
  gemm_big_k<<<dim3(16, 16, 8), 256, 0, stream>>>(pmat, Bm, Ladj);

  // stage B prep: inverse NS (residual form), X0 = c*I, R0 = I - c*Ladj
  sumsq_k<<<256, 256, 0, stream>>>(Ladj, KK, &scal[S_SS_LADJ]);
  derive_k<<<1, 1, 0, stream>>>(&scal[S_SS_LADJ], &scal[S_INV_C1], nullptr);
  initinv_k<<<KK / 256, 256, 0, stream>>>(Ladj, &scal[S_INV_C1], Xa, Ra);

  // stage C prep: coupled sqrt NS on S0/||S0||_F
  sumsq_k<<<256, 256, 0, stream>>>(S0, KK, &scal[S_SS_S0]);
  derive_k<<<1, 1, 0, stream>>>(&scal[S_SS_S0], &scal[S_INV_C0], &scal[S_QRT_C0]);
  scale_k<<<KK / 256, 256, 0, stream>>>(S0, &scal[S_INV_C0], Ya);
  setid_const_k<<<KK / 256, 256, 0, stream>>>(Za, 1.0f);

  // interleaved B+C: 18 rounds of {1 sqrt iter + 1 inv iter}, then 6 inv-only
  for (int r = 0; r < 18; ++r) {
    bcA_k<<<dim3(16, 16, 4), 256, 0, stream>>>(Za, Ya, Pm0, Pm1, Xa, Ra, Xb, Rb);
    yz_k<<<dim3(16, 16, 2), 256, 0, stream>>>(Ya, Za, Pm0, Pm1, Yb, Zb);
    float* t = Xa; Xa = Xb; Xb = t;
    t = Ra; Ra = Rb; Rb = t;
    t = Ya; Ya = Yb; Yb = t;
    t = Za; Za = Zb; Zb = t;
  }
  for (int r = 0; r < 6; ++r) {
    invduo_k<<<dim3(16, 16, 2), 256, 0, stream>>>(Xa, Ra, Xb, Rb);
    float* t = Xa; Xa = Xb; Xb = t;
    t = Ra; Ra = Rb; Rb = t;
  }
  trace_k<<<1, 512, 0, stream>>>(Xa, &scal[S_TR_X]);
  scale_k<<<KK / 256, 256, 0, stream>>>(Ya, &scal[S_QRT_C0], S0h);
  trace_k<<<1, 512, 0, stream>>>(S0, &scal[S_TR_S0]);

  // stage D: G = S0h @ S1 @ S0h (symmetrized), then tr(sqrtm(G))
  gemm_kk<<<dim3(16, 16), 256, 0, stream>>>(S0h, Xa, nullptr, TMP, 1.0f, 0.0f);
  gemm_kk<<<dim3(16, 16), 256, 0, stream>>>(TMP, S0h, nullptr, G, 1.0f, 0.0f);
  sym_k<<<KK / 256, 256, 0, stream>>>(G, TMP);
  sumsq_k<<<256, 256, 0, stream>>>(TMP, KK, &scal[S_SS_G]);
  derive_k<<<1, 1, 0, stream>>>(&scal[S_SS_G], &scal[S_INV_CG], &scal[S_QRT_CG]);
  scale_k<<<KK / 256, 256, 0, stream>>>(TMP, &scal[S_INV_CG], Ya);
  setid_const_k<<<KK / 256, 256, 0, stream>>>(Za, 1.0f);
  for (int r = 0; r < 26; ++r) {
    pm_k<<<dim3(16, 16, 2), 256, 0, stream>>>(Za, Ya, Pm0, Pm1);
    yz_k<<<dim3(16, 16, 2), 256, 0, stream>>>(Ya, Za, Pm0, Pm1, Yb, Zb);
    float* t = Ya; Ya = Yb; Yb = t;
    t = Za; Za = Zb; Zb = t;
  }
  trace_k<<<1, 512, 0, stream>>>(Ya, &scal[S_TR_YG]);

  final_k<<<1, 1, 0, stream>>>(scal, out);
}

// Round 6
// 1610.234 us; speedup vs baseline: 4.4415x; 2.1307x over previous
//
#include <hip/hip_runtime.h>
#include <math.h>

#define VN 8192
#define DN 128
#define EN 262144
#define KD 512
#define KK (KD*KD)

// scalar slots
#define S_SS_LADJ 0
#define S_INV_C1  1
#define S_SS_S0   2
#define S_INV_C0  3
#define S_QRT_C0  4
#define S_SS_G    5
#define S_INV_CG  6
#define S_QRT_CG  7
#define S_TR_X    8
#define S_TR_S0   9
#define S_TR_YG   10

typedef __attribute__((ext_vector_type(8))) __bf16 bf16x8;
typedef __attribute__((ext_vector_type(4))) float f32x4;

static __device__ __forceinline__ float waveReduceAdd(float v) {
#pragma unroll
  for (int o = 32; o; o >>= 1) v += __shfl_xor(v, o);
  return v;
}

// round-to-nearest-even f32 -> bf16 bits, and back
static __device__ __forceinline__ ushort f2b(float f) {
  unsigned x = __float_as_uint(f);
  unsigned r = (x + 0x7fffu + ((x >> 16) & 1u)) >> 16;
  return (ushort)r;
}
static __device__ __forceinline__ float b2f(ushort u) {
  return __uint_as_float((unsigned)u << 16);
}

// ---------- stage A: graph -> L_adj (fp32, unchanged from round 1) ----------

__global__ __launch_bounds__(256) void transpose_k(const float* __restrict__ in,
                                                   float* __restrict__ out) {
  __shared__ float s[32][33];
  int tx = threadIdx.x & 31, ty = threadIdx.x >> 5;
  int v0 = blockIdx.x * 32, k0 = blockIdx.y * 32;
  for (int r = ty; r < 32; r += 8) s[r][tx] = in[(size_t)(k0 + r) * VN + v0 + tx];
  __syncthreads();
  for (int r = ty; r < 32; r += 8) out[(size_t)(v0 + r) * KD + k0 + tx] = s[tx][r];
}

__global__ __launch_bounds__(256) void count_k(const float* __restrict__ x,
                                               const int* __restrict__ ei,
                                               int* __restrict__ ea, int* __restrict__ eb,
                                               float* __restrict__ ew,
                                               int* __restrict__ cnt,
                                               unsigned int* __restrict__ bitmap) {
  int e = (int)(((unsigned)blockIdx.x * 256u + threadIdx.x) >> 6);
  int lane = threadIdx.x & 63;
  if (e >= EN) return;
  int i = ei[e], j = ei[EN + e];
  int a = i < j ? i : j;
  int b = i < j ? j : i;
  int ok = 0;
  if (lane == 0) {
    if (i != j) {
      unsigned key = (unsigned)a * (unsigned)VN + (unsigned)b;
      unsigned m = 1u << (key & 31u);
      unsigned old = atomicOr(bitmap + (key >> 5), m);
      ok = (old & m) ? 0 : 1;
    }
  }
  ok = __shfl(ok, 0);
  if (!ok) { if (lane == 0) ea[e] = -1; return; }
  float d0 = x[a * DN + lane]      - x[b * DN + lane];
  float d1 = x[a * DN + 64 + lane] - x[b * DN + 64 + lane];
  float s = d0 * d0 + d1 * d1;
  s = waveReduceAdd(s);
  if (lane == 0) {
    ea[e] = a; eb[e] = b; ew[e] = expf(-s);
    atomicAdd(cnt + a, 1);
    atomicAdd(cnt + b, 1);
  }
}

__global__ __launch_bounds__(1024) void scan_k(const int* __restrict__ cnt,
                                               int* __restrict__ rowptr,
                                               int* __restrict__ cursor) {
  __shared__ int sd[1024];
  __shared__ int carry;
  int tid = threadIdx.x;
  if (tid == 0) { carry = 0; rowptr[0] = 0; }
  __syncthreads();
  for (int c = 0; c < VN / 1024; ++c) {
    int v = c * 1024 + tid;
    int xv = cnt[v];
    sd[tid] = xv;
    __syncthreads();
    for (int off = 1; off < 1024; off <<= 1) {
      int t = (tid >= off) ? sd[tid - off] : 0;
      __syncthreads();
      sd[tid] += t;
      __syncthreads();
    }
    int incl = sd[tid];
    int base = carry;
    rowptr[v + 1] = base + incl;
    cursor[v] = base + incl - xv;
    __syncthreads();
    if (tid == 1023) carry = base + incl;
    __syncthreads();
  }
}

__global__ __launch_bounds__(256) void fill_k(const int* __restrict__ ea, const int* __restrict__ eb,
                                              const float* __restrict__ ew,
                                              int* __restrict__ cursor,
                                              int* __restrict__ adjj, float* __restrict__ adjw) {
  int e = blockIdx.x * 256 + threadIdx.x;
  if (e >= EN) return;
  int a = ea[e];
  if (a < 0) return;
  int b = eb[e];
  float w = ew[e];
  int p = atomicAdd(cursor + a, 1); adjj[p] = b; adjw[p] = w;
  int q = atomicAdd(cursor + b, 1); adjj[q] = a; adjw[q] = w;
}

// round-1 form: one vertex per block, k = threadIdx (full row, 201us measured)
__global__ __launch_bounds__(512) void buildB_k(const float* __restrict__ pmatT,
                                                const int* __restrict__ rowptr,
                                                const int* __restrict__ adjj,
                                                const float* __restrict__ adjw,
                                                float* __restrict__ Bout) {
  int v = blockIdx.x;
  int k = threadIdx.x;
  int s = rowptr[v], e = rowptr[v + 1];
  float acc = 0.f, sw = 0.f;
  for (int p = s; p < e; ++p) {
    int jj = adjj[p];
    float w = adjw[p];
    acc += w * pmatT[(size_t)jj * KD + k];
    sw += w;
  }
  Bout[(size_t)v * KD + k] = sw * pmatT[(size_t)v * KD + k] - acc;
}

// C(512x512) += pmat(512x8192) @ B(8192x512), split-k over blockIdx.z
__global__ __launch_bounds__(256) void gemm_big_k(const float* __restrict__ A,
                                                  const float* __restrict__ B,
                                                  float* __restrict__ C) {
  __shared__ __align__(16) float As[32][34];
  __shared__ __align__(16) float Bs[32][34];
  int tid = threadIdx.x;
  int tx = tid & 15, ty = tid >> 4;
  int n0 = blockIdx.x * 32, m0 = blockIdx.y * 32;
  int kbase = blockIdx.z * (VN / 8);
  float a00 = 0.f, a01 = 0.f, a10 = 0.f, a11 = 0.f;
  for (int kt = kbase; kt < kbase + VN / 8; kt += 32) {
#pragma unroll
    for (int u = 0; u < 4; ++u) {
      int li = tid * 4 + u;
      int r = li >> 5, c = li & 31;
      As[c][r] = A[(size_t)(m0 + r) * VN + kt + c];
      Bs[r][c] = B[(size_t)(kt + r) * KD + n0 + c];
    }
    __syncthreads();
#pragma unroll
    for (int k = 0; k < 32; ++k) {
      float2 av = *(const float2*)&As[k][2 * ty];
      float2 bv = *(const float2*)&Bs[k][2 * tx];
      a00 += av.x * bv.x; a01 += av.x * bv.y;
      a10 += av.y * bv.x; a11 += av.y * bv.y;
    }
    __syncthreads();
  }
  int m = m0 + 2 * ty, n = n0 + 2 * tx;
  atomicAdd(&C[m * KD + n], a00);
  atomicAdd(&C[m * KD + n + 1], a01);
  atomicAdd(&C[(m + 1) * KD + n], a10);
  atomicAdd(&C[(m + 1) * KD + n + 1], a11);
}

// ---------- split-bf16 MFMA K x K GEMM ----------
// Slot layout (2 MB): [0,1M) f32 master, [1M,1.5M) bf16 hi, [1.5M,2M) bf16 lo.
// Computes C = alpha*(A@B) + beta*D using Ah*Bh + Ah*Bl + Al*Bh (fp32 acc).
// B-operand is read ROW-major (all B-operands in the NS chains are symmetric,
// so row-major == the required B^T form).

struct SmemT { ushort a[2][64][40]; ushort b[2][64][40]; };  // 20480 B

static __device__ __forceinline__ void mgemm_s(SmemT* sm,
    const float* Asl, const float* Bsl, const float* Dsl, float* Csl,
    float alpha, float beta, int wsplit) {
  const ushort* Ah = (const ushort*)(Asl + KK);
  const ushort* Al = Ah + KK;
  const ushort* Bh = (const ushort*)(Bsl + KK);
  const ushort* Bl = Bh + KK;
  int tid = threadIdx.x;
  int lane = tid & 63, wave = tid >> 6;
  int wr = wave >> 1, wc = wave & 1;           // 2x2 wave grid, 32x32 each
  int fr = lane & 15, fq = lane >> 4;
  int m0 = blockIdx.y * 64, n0 = blockIdx.x * 64;
  int sr = tid >> 2, skc = (tid & 3) * 8;      // staging: row, k-chunk (16B)
  f32x4 acc[2][2] = {};
  for (int kt = 0; kt < KD; kt += 32) {
    *(uint4*)&sm->a[0][sr][skc] = *(const uint4*)&Ah[(size_t)(m0 + sr) * KD + kt + skc];
    *(uint4*)&sm->a[1][sr][skc] = *(const uint4*)&Al[(size_t)(m0 + sr) * KD + kt + skc];
    *(uint4*)&sm->b[0][sr][skc] = *(const uint4*)&Bh[(size_t)(n0 + sr) * KD + kt + skc];
    *(uint4*)&sm->b[1][sr][skc] = *(const uint4*)&Bl[(size_t)(n0 + sr) * KD + kt + skc];
    __syncthreads();
    bf16x8 ah[2], al[2], bh[2], bl[2];
#pragma unroll
    for (int m = 0; m < 2; ++m) {
      ah[m] = *(const bf16x8*)&sm->a[0][wr * 32 + m * 16 + fr][fq * 8];
      al[m] = *(const bf16x8*)&sm->a[1][wr * 32 + m * 16 + fr][fq * 8];
    }
#pragma unroll
    for (int n = 0; n < 2; ++n) {
      bh[n] = *(const bf16x8*)&sm->b[0][wc * 32 + n * 16 + fr][fq * 8];
      bl[n] = *(const bf16x8*)&sm->b[1][wc * 32 + n * 16 + fr][fq * 8];
    }
#pragma unroll
    for (int m = 0; m < 2; ++m)
#pragma unroll
      for (int n = 0; n < 2; ++n) {
        acc[m][n] = __builtin_amdgcn_mfma_f32_16x16x32_bf16(ah[m], bh[n], acc[m][n], 0, 0, 0);
        acc[m][n] = __builtin_amdgcn_mfma_f32_16x16x32_bf16(ah[m], bl[n], acc[m][n], 0, 0, 0);
        acc[m][n] = __builtin_amdgcn_mfma_f32_16x16x32_bf16(al[m], bh[n], acc[m][n], 0, 0, 0);
      }
    __syncthreads();
  }
  ushort* Ch = (ushort*)(Csl + KK);
  ushort* Cl = Ch + KK;
#pragma unroll
  for (int m = 0; m < 2; ++m)
#pragma unroll
    for (int n = 0; n < 2; ++n) {
      int col = n0 + wc * 32 + n * 16 + fr;
#pragma unroll
      for (int j = 0; j < 4; ++j) {
        int row = m0 + wr * 32 + m * 16 + fq * 4 + j;
        float v = alpha * acc[m][n][j];
        if (beta != 0.f) v += beta * Dsl[row * KD + col];
        Csl[row * KD + col] = v;
        if (wsplit) {
          ushort h = f2b(v);
          Ch[row * KD + col] = h;
          Cl[row * KD + col] = f2b(v - b2f(h));
        }
      }
    }
}

// z=0: Pm = Za@Ya ; z=1: Xb = Xa@Ra + Xa ; z=2: Rb = Ra@Ra
__global__ __launch_bounds__(256) void bc3_k(const float* Za, const float* Ya, float* Pm,
                                             const float* Xa, const float* Ra,
                                             float* Xb, float* Rb) {
  __shared__ SmemT sm;
  int z = blockIdx.z;
  if (z == 0)      mgemm_s(&sm, Za, Ya, nullptr, Pm, 1.f, 0.f, 1);
  else if (z == 1) mgemm_s(&sm, Xa, Ra, Xa, Xb, 1.f, 1.f, 1);
  else             mgemm_s(&sm, Ra, Ra, nullptr, Rb, 1.f, 0.f, 1);
}

// z=0: Yb = -0.5*Ya@Pm + 1.5*Ya ; z=1: Zb = -0.5*Pm@Za + 1.5*Za
__global__ __launch_bounds__(256) void yz2_k(const float* Ya, const float* Za, const float* Pm,
                                             float* Yb, float* Zb) {
  __shared__ SmemT sm;
  if (blockIdx.z == 0) mgemm_s(&sm, Ya, Pm, Ya, Yb, -0.5f, 1.5f, 1);
  else                 mgemm_s(&sm, Pm, Za, Za, Zb, -0.5f, 1.5f, 1);
}

__global__ __launch_bounds__(256) void inv2_k(const float* Xa, const float* Ra,
                                              float* Xb, float* Rb) {
  __shared__ SmemT sm;
  if (blockIdx.z == 0) mgemm_s(&sm, Xa, Ra, Xa, Xb, 1.f, 1.f, 1);
  else                 mgemm_s(&sm, Ra, Ra, nullptr, Rb, 1.f, 0.f, 1);
}

__global__ __launch_bounds__(256) void pm1_k(const float* Za, const float* Ya, float* Pm) {
  __shared__ SmemT sm;
  mgemm_s(&sm, Za, Ya, nullptr, Pm, 1.f, 0.f, 1);
}

__global__ __launch_bounds__(256) void one_k(const float* A, const float* B, float* C,
                                             int wsplit) {
  __shared__ SmemT sm;
  mgemm_s(&sm, A, B, nullptr, C, 1.f, 0.f, wsplit);
}

// ---------- small utility kernels ----------

__global__ __launch_bounds__(256) void sumsq_k(const float* __restrict__ A, int n,
                                               float* __restrict__ slot) {
  float s = 0.f;
  for (int i = blockIdx.x * 256 + threadIdx.x; i < n; i += gridDim.x * 256) {
    float v = A[i];
    s += v * v;
  }
  __shared__ float p[4];
  s = waveReduceAdd(s);
  if ((threadIdx.x & 63) == 0) p[threadIdx.x >> 6] = s;
  __syncthreads();
  if (threadIdx.x == 0) atomicAdd(slot, p[0] + p[1] + p[2] + p[3]);
}

__global__ __launch_bounds__(512) void trace_k(const float* __restrict__ A,
                                               float* __restrict__ slot) {
  float v = A[(size_t)threadIdx.x * KD + threadIdx.x];
  __shared__ float p[8];
  v = waveReduceAdd(v);
  if ((threadIdx.x & 63) == 0) p[threadIdx.x >> 6] = v;
  __syncthreads();
  if (threadIdx.x == 0) {
    float t = 0.f;
    for (int i = 0; i < 8; ++i) t += p[i];
    slot[0] = t;
  }
}

__global__ void derive_k(const float* __restrict__ in, float* __restrict__ o_rsqrt,
                         float* __restrict__ o_qroot) {
  float x = in[0];
  o_rsqrt[0] = 1.0f / sqrtf(x);
  if (o_qroot) o_qroot[0] = powf(x, 0.25f);
}

__global__ __launch_bounds__(256) void setid_const_k(float* __restrict__ C, float val) {
  int idx = blockIdx.x * 256 + threadIdx.x;
  int r = idx >> 9, c = idx & (KD - 1);
  C[idx] = (r == c) ? val : 0.0f;
}

// X0 = c*I ; R0 = I - c*Ladj  (both written as {f32, hi, lo})
__global__ __launch_bounds__(256) void initinv_split_k(const float* __restrict__ Ladj,
                                                       const float* __restrict__ s,
                                                       float* __restrict__ X,
                                                       float* __restrict__ R) {
  int idx = blockIdx.x * 256 + threadIdx.x;
  int r = idx >> 9, c = idx & (KD - 1);
  float cv = s[0];
  float id = (r == c) ? 1.f : 0.f;
  float xv = id * cv;
  float rv = id - cv * Ladj[idx];
  ushort* Xh = (ushort*)(X + KK); ushort* Xl = Xh + KK;
  ushort* Rh = (ushort*)(R + KK); ushort* Rl = Rh + KK;
  X[idx] = xv; ushort h = f2b(xv); Xh[idx] = h; Xl[idx] = f2b(xv - b2f(h));
  R[idx] = rv; h = f2b(rv);        Rh[idx] = h; Rl[idx] = f2b(rv - b2f(h));
}

__global__ __launch_bounds__(256) void setid_split_k(float* __restrict__ C, float val) {
  int idx = blockIdx.x * 256 + threadIdx.x;
  int r = idx >> 9, c = idx & (KD - 1);
  float v = (r == c) ? val : 0.0f;
  ushort* Chh = (ushort*)(C + KK); ushort* Cll = Chh + KK;
  C[idx] = v; ushort h = f2b(v); Chh[idx] = h; Cll[idx] = f2b(v - b2f(h));
}

__global__ __launch_bounds__(256) void scale_split_k(const float* __restrict__ A,
                                                     const float* __restrict__ s,
                                                     float* __restrict__ C) {
  int idx = blockIdx.x * 256 + threadIdx.x;
  float v = A[idx] * s[0];
  ushort* Chh = (ushort*)(C + KK); ushort* Cll = Chh + KK;
  C[idx] = v; ushort h = f2b(v); Chh[idx] = h; Cll[idx] = f2b(v - b2f(h));
}

__global__ __launch_bounds__(256) void sym_k(const float* __restrict__ G,
                                             float* __restrict__ Out) {
  int idx = blockIdx.x * 256 + threadIdx.x;
  int r = idx >> 9, c = idx & (KD - 1);
  Out[idx] = 0.5f * (G[idx] + G[c * KD + r]);
}

__global__ void final_k(const float* __restrict__ scal, float* __restrict__ out) {
  out[0] = scal[S_TR_X] + scal[S_TR_S0] - 2.0f * scal[S_QRT_CG] * scal[S_TR_YG];
}

// ---------- host ----------

extern "C" void kernel_launch(void* const* d_in, const int* in_sizes, int n_in,
                              void* d_out, int out_size, void* d_ws, size_t ws_size,
                              hipStream_t stream) {
  (void)in_sizes; (void)n_in; (void)out_size; (void)ws_size;
  const float* x    = (const float*)d_in[0];  // V x D
  const float* S0   = (const float*)d_in[1];  // K x K
  const int*   ei   = (const int*)d_in[2];    // 2 x E
  const float* pmat = (const float*)d_in[3];  // K x V
  float* out = (float*)d_out;
  char* ws = (char*)d_ws;

  const size_t MB = 1u << 20;
  // region0 [0,8M): bitmap during count_k; then Ladj [0,1M) + G [1M,2M)
  unsigned* bitmap = (unsigned*)ws;
  float* Ladj = (float*)ws;
  float* Gs   = (float*)(ws + 1 * MB);
  // region1 [8M,40M): pmatT [8M,24M) + Bm [24M,40M) during stage A;
  // then 11 x 2MB split slots [8M,30M) (all slot writes happen after gemm_big).
  float* pmatT = (float*)(ws + 8 * MB);
  float* Bm    = (float*)(ws + 24 * MB);
  float* SL[11];
  for (int i = 0; i < 11; ++i) SL[i] = (float*)(ws + 8 * MB + (size_t)i * 2 * MB);
  float *Xa = SL[0], *Xb = SL[1], *Ra = SL[2], *Rb = SL[3];
  float *Ya = SL[4], *Yb = SL[5], *Za = SL[6], *Zb = SL[7];
  float *Pm = SL[8], *S0h = SL[9], *TMP = SL[10];
  // region2 [40M, ...): edge/CSR arrays + scalars
  size_t off = 40 * MB;
  int*   ea    = (int*)(ws + off);   off += (size_t)EN * 4;
  int*   eb    = (int*)(ws + off);   off += (size_t)EN * 4;
  float* ew    = (float*)(ws + off); off += (size_t)EN * 4;
  int*   cnt   = (int*)(ws + off);   off += (size_t)VN * 4;
  int*  rowptr = (int*)(ws + off);   off += (size_t)(VN + 2) * 4;
  int*  cursor = (int*)(ws + off);   off += (size_t)VN * 4;
  int*   adjj  = (int*)(ws + off);   off += (size_t)2 * EN * 4;
  float* adjw  = (float*)(ws + off); off += (size_t)2 * EN * 4;
  float* scal  = (float*)(ws + off); off += 64 * 4;

  hipMemsetAsync(bitmap, 0, (size_t)VN * VN / 8, stream);
  hipMemsetAsync(cnt, 0, (size_t)VN * 4, stream);
  hipMemsetAsync(scal, 0, 64 * 4, stream);

  // stage A: graph construction -> L_adj (fp32)
  transpose_k<<<dim3(VN / 32, KD / 32), 256, 0, stream>>>(pmat, pmatT);
  count_k<<<EN / 4, 256, 0, stream>>>(x, ei, ea, eb, ew, cnt, bitmap);
  scan_k<<<1, 1024, 0, stream>>>(cnt, rowptr, cursor);
  fill_k<<<EN / 256, 256, 0, stream>>>(ea, eb, ew, cursor, adjj, adjw);
  buildB_k<<<VN, 512, 0, stream>>>(pmatT, rowptr, adjj, adjw, Bm);
  setid_const_k<<<KK / 256, 256, 0, stream>>>(Ladj, 1e-5f);
  gemm_big_k<<<dim3(16, 16, 8), 256, 0, stream>>>(pmat, Bm, Ladj);

  // stage B prep: residual-form inverse NS
  sumsq_k<<<256, 256, 0, stream>>>(Ladj, KK, &scal[S_SS_LADJ]);
  derive_k<<<1, 1, 0, stream>>>(&scal[S_SS_LADJ], &scal[S_INV_C1], nullptr);
  initinv_split_k<<<KK / 256, 256, 0, stream>>>(Ladj, &scal[S_INV_C1], Xa, Ra);

  // stage C prep: coupled sqrt NS on S0/||S0||_F
  sumsq_k<<<256, 256, 0, stream>>>(S0, KK, &scal[S_SS_S0]);
  derive_k<<<1, 1, 0, stream>>>(&scal[S_SS_S0], &scal[S_INV_C0], &scal[S_QRT_C0]);
  scale_split_k<<<KK / 256, 256, 0, stream>>>(S0, &scal[S_INV_C0], Ya);
  setid_split_k<<<KK / 256, 256, 0, stream>>>(Za, 1.0f);

  // interleave: 16 rounds of {sqrt iter + inv iter}, then 2 inv-only (inv=18, sqrt=16)
  for (int r = 0; r < 16; ++r) {
    bc3_k<<<dim3(8, 8, 3), 256, 0, stream>>>(Za, Ya, Pm, Xa, Ra, Xb, Rb);
    yz2_k<<<dim3(8, 8, 2), 256, 0, stream>>>(Ya, Za, Pm, Yb, Zb);
    float* t = Xa; Xa = Xb; Xb = t;
    t = Ra; Ra = Rb; Rb = t;
    t = Ya; Ya = Yb; Yb = t;
    t = Za; Za = Zb; Zb = t;
  }
  for (int r = 0; r < 2; ++r) {
    inv2_k<<<dim3(8, 8, 2), 256, 0, stream>>>(Xa, Ra, Xb, Rb);
    float* t = Xa; Xa = Xb; Xb = t;
    t = Ra; Ra = Rb; Rb = t;
  }
  trace_k<<<1, 512, 0, stream>>>(Xa, &scal[S_TR_X]);
  scale_split_k<<<KK / 256, 256, 0, stream>>>(Ya, &scal[S_QRT_C0], S0h);
  trace_k<<<1, 512, 0, stream>>>(S0, &scal[S_TR_S0]);

  // stage D: G = S0h @ S1 @ S0h, then tr(sqrtm(G))  (22 iters)
  one_k<<<dim3(8, 8, 1), 256, 0, stream>>>(S0h, Xa, TMP, 1);
  one_k<<<dim3(8, 8, 1), 256, 0, stream>>>(TMP, S0h, Gs, 0);
  sym_k<<<KK / 256, 256, 0, stream>>>(Gs, TMP);   // TMP.f32 = sym(G)
  sumsq_k<<<256, 256, 0, stream>>>(TMP, KK, &scal[S_SS_G]);
  derive_k<<<1, 1, 0, stream>>>(&scal[S_SS_G], &scal[S_INV_CG], &scal[S_QRT_CG]);
  scale_split_k<<<KK / 256, 256, 0, stream>>>(TMP, &scal[S_INV_CG], Ya);
  setid_split_k<<<KK / 256, 256, 0, stream>>>(Za, 1.0f);
  for (int r = 0; r < 22; ++r) {
    pm1_k<<<dim3(8, 8, 1), 256, 0, stream>>>(Za, Ya, Pm);
    yz2_k<<<dim3(8, 8, 2), 256, 0, stream>>>(Ya, Za, Pm, Yb, Zb);
    float* t = Ya; Ya = Yb; Yb = t;
    t = Za; Za = Zb; Zb = t;
  }
  trace_k<<<1, 512, 0, stream>>>(Ya, &scal[S_TR_YG]);

  final_k<<<1, 1, 0, stream>>>(scal, out);
}

// Round 12
// 1579.912 us; speedup vs baseline: 4.5267x; 1.0192x over previous
//
#include <hip/hip_runtime.h>
#include <math.h>

#define VN 8192
#define DN 128
#define EN 262144
#define KD 512
#define KK (KD*KD)

// scalar slots
#define S_SS_LADJ 0
#define S_INV_C1  1
#define S_SS_S0   2
#define S_INV_C0  3
#define S_QRT_C0  4
#define S_SS_G    5
#define S_INV_CG  6
#define S_QRT_CG  7
#define S_TR_X    8
#define S_TR_S0   9
#define S_TR_YG   10

typedef __attribute__((ext_vector_type(8))) __bf16 bf16x8;
typedef __attribute__((ext_vector_type(4))) float f32x4;

static __device__ __forceinline__ float waveReduceAdd(float v) {
#pragma unroll
  for (int o = 32; o; o >>= 1) v += __shfl_xor(v, o);
  return v;
}

// round-to-nearest-even f32 -> bf16 bits, and back
static __device__ __forceinline__ ushort f2b(float f) {
  unsigned x = __float_as_uint(f);
  unsigned r = (x + 0x7fffu + ((x >> 16) & 1u)) >> 16;
  return (ushort)r;
}
static __device__ __forceinline__ float b2f(ushort u) {
  return __uint_as_float((unsigned)u << 16);
}

// ---------- stage A: graph -> L_adj (fp32, proven path) ----------

__global__ __launch_bounds__(256) void transpose_k(const float* __restrict__ in,
                                                   float* __restrict__ out) {
  __shared__ float s[32][33];
  int tx = threadIdx.x & 31, ty = threadIdx.x >> 5;
  int v0 = blockIdx.x * 32, k0 = blockIdx.y * 32;
  for (int r = ty; r < 32; r += 8) s[r][tx] = in[(size_t)(k0 + r) * VN + v0 + tx];
  __syncthreads();
  for (int r = ty; r < 32; r += 8) out[(size_t)(v0 + r) * KD + k0 + tx] = s[tx][r];
}

__global__ __launch_bounds__(256) void count_k(const float* __restrict__ x,
                                               const int* __restrict__ ei,
                                               int* __restrict__ ea, int* __restrict__ eb,
                                               float* __restrict__ ew,
                                               int* __restrict__ cnt,
                                               unsigned int* __restrict__ bitmap) {
  int e = (int)(((unsigned)blockIdx.x * 256u + threadIdx.x) >> 6);
  int lane = threadIdx.x & 63;
  if (e >= EN) return;
  int i = ei[e], j = ei[EN + e];
  int a = i < j ? i : j;
  int b = i < j ? j : i;
  int ok = 0;
  if (lane == 0) {
    if (i != j) {
      unsigned key = (unsigned)a * (unsigned)VN + (unsigned)b;
      unsigned m = 1u << (key & 31u);
      unsigned old = atomicOr(bitmap + (key >> 5), m);
      ok = (old & m) ? 0 : 1;
    }
  }
  ok = __shfl(ok, 0);
  if (!ok) { if (lane == 0) ea[e] = -1; return; }
  float d0 = x[a * DN + lane]      - x[b * DN + lane];
  float d1 = x[a * DN + 64 + lane] - x[b * DN + 64 + lane];
  float s = d0 * d0 + d1 * d1;
  s = waveReduceAdd(s);
  if (lane == 0) {
    ea[e] = a; eb[e] = b; ew[e] = expf(-s);
    atomicAdd(cnt + a, 1);
    atomicAdd(cnt + b, 1);
  }
}

__global__ __launch_bounds__(1024) void scan_k(const int* __restrict__ cnt,
                                               int* __restrict__ rowptr,
                                               int* __restrict__ cursor) {
  __shared__ int sd[1024];
  __shared__ int carry;
  int tid = threadIdx.x;
  if (tid == 0) { carry = 0; rowptr[0] = 0; }
  __syncthreads();
  for (int c = 0; c < VN / 1024; ++c) {
    int v = c * 1024 + tid;
    int xv = cnt[v];
    sd[tid] = xv;
    __syncthreads();
    for (int off = 1; off < 1024; off <<= 1) {
      int t = (tid >= off) ? sd[tid - off] : 0;
      __syncthreads();
      sd[tid] += t;
      __syncthreads();
    }
    int incl = sd[tid];
    int base = carry;
    rowptr[v + 1] = base + incl;
    cursor[v] = base + incl - xv;
    __syncthreads();
    if (tid == 1023) carry = base + incl;
    __syncthreads();
  }
}

__global__ __launch_bounds__(256) void fill_k(const int* __restrict__ ea, const int* __restrict__ eb,
                                              const float* __restrict__ ew,
                                              int* __restrict__ cursor,
                                              int* __restrict__ adjj, float* __restrict__ adjw) {
  int e = blockIdx.x * 256 + threadIdx.x;
  if (e >= EN) return;
  int a = ea[e];
  if (a < 0) return;
  int b = eb[e];
  float w = ew[e];
  int p = atomicAdd(cursor + a, 1); adjj[p] = b; adjw[p] = w;
  int q = atomicAdd(cursor + b, 1); adjj[q] = a; adjw[q] = w;
}

__global__ __launch_bounds__(512) void buildB_k(const float* __restrict__ pmatT,
                                                const int* __restrict__ rowptr,
                                                const int* __restrict__ adjj,
                                                const float* __restrict__ adjw,
                                                float* __restrict__ Bout) {
  int v = blockIdx.x;
  int k = threadIdx.x;
  int s = rowptr[v], e = rowptr[v + 1];
  float a0 = 0.f, a1 = 0.f, a2 = 0.f, a3 = 0.f, sw = 0.f;
  int p = s;
  for (; p + 4 <= e; p += 4) {
    int j0 = adjj[p], j1 = adjj[p + 1], j2 = adjj[p + 2], j3 = adjj[p + 3];
    float w0 = adjw[p], w1 = adjw[p + 1], w2 = adjw[p + 2], w3 = adjw[p + 3];
    a0 += w0 * pmatT[(size_t)j0 * KD + k];
    a1 += w1 * pmatT[(size_t)j1 * KD + k];
    a2 += w2 * pmatT[(size_t)j2 * KD + k];
    a3 += w3 * pmatT[(size_t)j3 * KD + k];
    sw += w0 + w1 + w2 + w3;
  }
  for (; p < e; ++p) {
    int jj = adjj[p];
    float w = adjw[p];
    a0 += w * pmatT[(size_t)jj * KD + k];
    sw += w;
  }
  Bout[(size_t)v * KD + k] = sw * pmatT[(size_t)v * KD + k] - (a0 + a1 + a2 + a3);
}

__global__ __launch_bounds__(256) void gemm_big_k(const float* __restrict__ A,
                                                  const float* __restrict__ B,
                                                  float* __restrict__ C) {
  __shared__ __align__(16) float As[32][34];
  __shared__ __align__(16) float Bs[32][34];
  int tid = threadIdx.x;
  int tx = tid & 15, ty = tid >> 4;
  int n0 = blockIdx.x * 32, m0 = blockIdx.y * 32;
  int kbase = blockIdx.z * (VN / 8);
  float a00 = 0.f, a01 = 0.f, a10 = 0.f, a11 = 0.f;
  for (int kt = kbase; kt < kbase + VN / 8; kt += 32) {
#pragma unroll
    for (int u = 0; u < 4; ++u) {
      int li = tid * 4 + u;
      int r = li >> 5, c = li & 31;
      As[c][r] = A[(size_t)(m0 + r) * VN + kt + c];
      Bs[r][c] = B[(size_t)(kt + r) * KD + n0 + c];
    }
    __syncthreads();
#pragma unroll
    for (int k = 0; k < 32; ++k) {
      float2 av = *(const float2*)&As[k][2 * ty];
      float2 bv = *(const float2*)&Bs[k][2 * tx];
      a00 += av.x * bv.x; a01 += av.x * bv.y;
      a10 += av.y * bv.x; a11 += av.y * bv.y;
    }
    __syncthreads();
  }
  int m = m0 + 2 * ty, n = n0 + 2 * tx;
  atomicAdd(&C[m * KD + n], a00);
  atomicAdd(&C[m * KD + n + 1], a01);
  atomicAdd(&C[(m + 1) * KD + n], a10);
  atomicAdd(&C[(m + 1) * KD + n + 1], a11);
}

// ---------- fp32 K x K GEMM (round-1 proven): C = alpha*A@B + beta*D ----------

static __device__ __forceinline__ void g32_body(const float* __restrict__ A,
                                                const float* __restrict__ B,
                                                const float* __restrict__ Dm,
                                                float* __restrict__ C,
                                                float alpha, float beta) {
  __shared__ __align__(16) float As[32][34];
  __shared__ __align__(16) float Bs[32][34];
  int tid = threadIdx.x;
  int tx = tid & 15, ty = tid >> 4;
  int n0 = blockIdx.x * 32, m0 = blockIdx.y * 32;
  float a00 = 0.f, a01 = 0.f, a10 = 0.f, a11 = 0.f;
  for (int kt = 0; kt < KD; kt += 32) {
#pragma unroll
    for (int u = 0; u < 4; ++u) {
      int li = tid * 4 + u;
      int r = li >> 5, c = li & 31;
      As[c][r] = A[(m0 + r) * KD + kt + c];
      Bs[r][c] = B[(kt + r) * KD + n0 + c];
    }
    __syncthreads();
#pragma unroll
    for (int k = 0; k < 32; ++k) {
      float2 av = *(const float2*)&As[k][2 * ty];
      float2 bv = *(const float2*)&Bs[k][2 * tx];
      a00 += av.x * bv.x; a01 += av.x * bv.y;
      a10 += av.y * bv.x; a11 += av.y * bv.y;
    }
    __syncthreads();
  }
  int m = m0 + 2 * ty, n = n0 + 2 * tx;
  float d00 = 0.f, d01 = 0.f, d10 = 0.f, d11 = 0.f;
  if (beta != 0.0f) {
    d00 = Dm[m * KD + n];       d01 = Dm[m * KD + n + 1];
    d10 = Dm[(m + 1) * KD + n]; d11 = Dm[(m + 1) * KD + n + 1];
  }
  C[m * KD + n]           = alpha * a00 + beta * d00;
  C[m * KD + n + 1]       = alpha * a01 + beta * d01;
  C[(m + 1) * KD + n]     = alpha * a10 + beta * d10;
  C[(m + 1) * KD + n + 1] = alpha * a11 + beta * d11;
}

__global__ __launch_bounds__(256) void gemm_kk(const float* __restrict__ A,
                                               const float* __restrict__ B,
                                               const float* __restrict__ Dm,
                                               float* __restrict__ C,
                                               float alpha, float beta) {
  g32_body(A, B, Dm, C, alpha, beta);
}

__global__ __launch_bounds__(256) void gemm_dual32(const float* A0, const float* B0,
                                                   const float* D0, float* C0,
                                                   const float* A1, const float* B1,
                                                   const float* D1, float* C1,
                                                   float alpha, float beta) {
  if (blockIdx.z == 0) g32_body(A0, B0, D0, C0, alpha, beta);
  else                 g32_body(A1, B1, D1, C1, alpha, beta);
}

// ---------- 2-way-split bf16 MFMA K x K GEMM (round-6 proven, 3 terms) ----------
// Slot (2 MB): [0,1M) f32 master, h [1M,1.5M), l [1.5M,2M).
// C = alpha*(A@B) + beta*D via Ah*Bh + Ah*Bl + Al*Bh (fp32 acc).
// B-operand read row-major (B^T form) — valid: all B operands symmetric.

struct SmemT { ushort a[2][64][40]; ushort b[2][64][40]; };  // 20480 B

static __device__ __forceinline__ void mgemm_s(SmemT* sm,
    const float* Asl, const float* Bsl, const float* Dsl, float* Csl,
    float alpha, float beta, int wsplit) {
  const ushort* Ah = (const ushort*)(Asl + KK);
  const ushort* Al = Ah + KK;
  const ushort* Bh = (const ushort*)(Bsl + KK);
  const ushort* Bl = Bh + KK;
  int tid = threadIdx.x;
  int lane = tid & 63, wave = tid >> 6;
  int wr = wave >> 1, wc = wave & 1;
  int fr = lane & 15, fq = lane >> 4;
  int m0 = blockIdx.y * 64, n0 = blockIdx.x * 64;
  int sr = tid >> 2, skc = (tid & 3) * 8;
  f32x4 acc[2][2] = {};
  for (int kt = 0; kt < KD; kt += 32) {
    *(uint4*)&sm->a[0][sr][skc] = *(const uint4*)&Ah[(size_t)(m0 + sr) * KD + kt + skc];
    *(uint4*)&sm->a[1][sr][skc] = *(const uint4*)&Al[(size_t)(m0 + sr) * KD + kt + skc];
    *(uint4*)&sm->b[0][sr][skc] = *(const uint4*)&Bh[(size_t)(n0 + sr) * KD + kt + skc];
    *(uint4*)&sm->b[1][sr][skc] = *(const uint4*)&Bl[(size_t)(n0 + sr) * KD + kt + skc];
    __syncthreads();
    bf16x8 ah[2], al[2], bh[2], bl[2];
#pragma unroll
    for (int m = 0; m < 2; ++m) {
      ah[m] = *(const bf16x8*)&sm->a[0][wr * 32 + m * 16 + fr][fq * 8];
      al[m] = *(const bf16x8*)&sm->a[1][wr * 32 + m * 16 + fr][fq * 8];
    }
#pragma unroll
    for (int n = 0; n < 2; ++n) {
      bh[n] = *(const bf16x8*)&sm->b[0][wc * 32 + n * 16 + fr][fq * 8];
      bl[n] = *(const bf16x8*)&sm->b[1][wc * 32 + n * 16 + fr][fq * 8];
    }
#pragma unroll
    for (int m = 0; m < 2; ++m)
#pragma unroll
      for (int n = 0; n < 2; ++n) {
        acc[m][n] = __builtin_amdgcn_mfma_f32_16x16x32_bf16(ah[m], bh[n], acc[m][n], 0, 0, 0);
        acc[m][n] = __builtin_amdgcn_mfma_f32_16x16x32_bf16(ah[m], bl[n], acc[m][n], 0, 0, 0);
        acc[m][n] = __builtin_amdgcn_mfma_f32_16x16x32_bf16(al[m], bh[n], acc[m][n], 0, 0, 0);
      }
    __syncthreads();
  }
  ushort* Ch = (ushort*)(Csl + KK);
  ushort* Cl = Ch + KK;
#pragma unroll
  for (int m = 0; m < 2; ++m)
#pragma unroll
    for (int n = 0; n < 2; ++n) {
      int col = n0 + wc * 32 + n * 16 + fr;
#pragma unroll
      for (int j = 0; j < 4; ++j) {
        int row = m0 + wr * 32 + m * 16 + fq * 4 + j;
        float v = alpha * acc[m][n][j];
        if (beta != 0.f) v += beta * Dsl[row * KD + col];
        Csl[row * KD + col] = v;
        if (wsplit) {
          ushort h = f2b(v);
          Ch[row * KD + col] = h;
          Cl[row * KD + col] = f2b(v - b2f(h));
        }
      }
    }
}

// z=0: Pm = Za@Ya ; z=1: Xb = Xa@Ra + Xa ; z=2: Rb = Ra@Ra
__global__ __launch_bounds__(256) void bc3_k(const float* Za, const float* Ya, float* Pm,
                                             const float* Xa, const float* Ra,
                                             float* Xb, float* Rb) {
  __shared__ SmemT sm;
  int z = blockIdx.z;
  if (z == 0)      mgemm_s(&sm, Za, Ya, nullptr, Pm, 1.f, 0.f, 1);
  else if (z == 1) mgemm_s(&sm, Xa, Ra, Xa, Xb, 1.f, 1.f, 1);
  else             mgemm_s(&sm, Ra, Ra, nullptr, Rb, 1.f, 0.f, 1);
}

// z=0: Yb = -0.5*Ya@Pm + 1.5*Ya ; z=1: Zb = -0.5*Pm@Za + 1.5*Za
__global__ __launch_bounds__(256) void yz2_k(const float* Ya, const float* Za, const float* Pm,
                                             float* Yb, float* Zb) {
  __shared__ SmemT sm;
  if (blockIdx.z == 0) mgemm_s(&sm, Ya, Pm, Ya, Yb, -0.5f, 1.5f, 1);
  else                 mgemm_s(&sm, Pm, Za, Za, Zb, -0.5f, 1.5f, 1);
}

__global__ __launch_bounds__(256) void pm1_k(const float* Za, const float* Ya, float* Pm) {
  __shared__ SmemT sm;
  mgemm_s(&sm, Za, Ya, nullptr, Pm, 1.f, 0.f, 1);
}

// ---------- small utility kernels ----------

__global__ __launch_bounds__(256) void sumsq_k(const float* __restrict__ A, int n,
                                               float* __restrict__ slot) {
  float s = 0.f;
  for (int i = blockIdx.x * 256 + threadIdx.x; i < n; i += gridDim.x * 256) {
    float v = A[i];
    s += v * v;
  }
  __shared__ float p[4];
  s = waveReduceAdd(s);
  if ((threadIdx.x & 63) == 0) p[threadIdx.x >> 6] = s;
  __syncthreads();
  if (threadIdx.x == 0) atomicAdd(slot, p[0] + p[1] + p[2] + p[3]);
}

__global__ __launch_bounds__(512) void trace_k(const float* __restrict__ A,
                                               float* __restrict__ slot) {
  float v = A[(size_t)threadIdx.x * KD + threadIdx.x];
  __shared__ float p[8];
  v = waveReduceAdd(v);
  if ((threadIdx.x & 63) == 0) p[threadIdx.x >> 6] = v;
  __syncthreads();
  if (threadIdx.x == 0) {
    float t = 0.f;
    for (int i = 0; i < 8; ++i) t += p[i];
    slot[0] = t;
  }
}

__global__ void derive_k(const float* __restrict__ in, float* __restrict__ o_rsqrt,
                         float* __restrict__ o_qroot) {
  float x = in[0];
  o_rsqrt[0] = 1.0f / sqrtf(x);
  if (o_qroot) o_qroot[0] = powf(x, 0.25f);
}

__global__ __launch_bounds__(256) void setid_const_k(float* __restrict__ C, float val) {
  int idx = blockIdx.x * 256 + threadIdx.x;
  int r = idx >> 9, c = idx & (KD - 1);
  C[idx] = (r == c) ? val : 0.0f;
}

// X0 = c*I ; R0 = I - c*Ladj  (both written as {f32, hi, lo})
__global__ __launch_bounds__(256) void initinv_split_k(const float* __restrict__ Ladj,
                                                       const float* __restrict__ s,
                                                       float* __restrict__ X,
                                                       float* __restrict__ R) {
  int idx = blockIdx.x * 256 + threadIdx.x;
  int r = idx >> 9, c = idx & (KD - 1);
  float cv = s[0];
  float id = (r == c) ? 1.f : 0.f;
  float xv = id * cv;
  float rv = id - cv * Ladj[idx];
  ushort* Xh = (ushort*)(X + KK); ushort* Xl = Xh + KK;
  ushort* Rh = (ushort*)(R + KK); ushort* Rl = Rh + KK;
  X[idx] = xv; ushort h = f2b(xv); Xh[idx] = h; Xl[idx] = f2b(xv - b2f(h));
  R[idx] = rv; h = f2b(rv);        Rh[idx] = h; Rl[idx] = f2b(rv - b2f(h));
}

__global__ __launch_bounds__(256) void setid_split_k(float* __restrict__ C, float val) {
  int idx = blockIdx.x * 256 + threadIdx.x;
  int r = idx >> 9, c = idx & (KD - 1);
  float v = (r == c) ? val : 0.0f;
  ushort* Chh = (ushort*)(C + KK); ushort* Cll = Chh + KK;
  C[idx] = v; ushort h = f2b(v); Chh[idx] = h; Cll[idx] = f2b(v - b2f(h));
}

__global__ __launch_bounds__(256) void scale_split_k(const float* __restrict__ A,
                                                     const float* __restrict__ s,
                                                     float* __restrict__ C) {
  int idx = blockIdx.x * 256 + threadIdx.x;
  float v = A[idx] * s[0];
  ushort* Chh = (ushort*)(C + KK); ushort* Cll = Chh + KK;
  C[idx] = v; ushort h = f2b(v); Chh[idx] = h; Cll[idx] = f2b(v - b2f(h));
}

// f32-only scale: C = A * s[0]
__global__ __launch_bounds__(256) void scale32_k(const float* __restrict__ A,
                                                 const float* __restrict__ s,
                                                 float* __restrict__ C) {
  int idx = blockIdx.x * 256 + threadIdx.x;
  C[idx] = A[idx] * s[0];
}

__global__ __launch_bounds__(256) void sym_k(const float* __restrict__ G,
                                             float* __restrict__ Out) {
  int idx = blockIdx.x * 256 + threadIdx.x;
  int r = idx >> 9, c = idx & (KD - 1);
  Out[idx] = 0.5f * (G[idx] + G[c * KD + r]);
}

__global__ void final_k(const float* __restrict__ scal, float* __restrict__ out) {
  out[0] = scal[S_TR_X] + scal[S_TR_S0] - 2.0f * scal[S_QRT_CG] * scal[S_TR_YG];
}

// ---------- host ----------

extern "C" void kernel_launch(void* const* d_in, const int* in_sizes, int n_in,
                              void* d_out, int out_size, void* d_ws, size_t ws_size,
                              hipStream_t stream) {
  (void)in_sizes; (void)n_in; (void)out_size; (void)ws_size;
  const float* x    = (const float*)d_in[0];  // V x D
  const float* S0   = (const float*)d_in[1];  // K x K
  const int*   ei   = (const int*)d_in[2];    // 2 x E
  const float* pmat = (const float*)d_in[3];  // K x V
  float* out = (float*)d_out;
  char* ws = (char*)d_ws;
  const size_t MB = 1u << 20;
  const size_t SLOT = 2 * MB;  // f32 + h + l

  // stage A regions
  unsigned* bitmap = (unsigned*)ws;           // [0,8M), dead after count_k
  float* pmatT = (float*)(ws + 8 * MB);       // [8,24M), dead after buildB_k
  float* Bm    = (float*)(ws + 24 * MB);      // [24,40M), dead after gemm_big_k
  float* Ladj  = (float*)(ws + 40 * MB);      // over ea (dead after fill_k); alive to inv polish
  float* Gs    = (float*)(ws + 41 * MB);      // over eb (dead after fill_k); stage D
  int*   ea     = (int*)(ws + 40 * MB);       // dead after fill_k
  int*   eb     = (int*)(ws + 41 * MB);       // dead after fill_k
  float* ew     = (float*)(ws + 42 * MB);     // dead after fill_k
  int*   adjj   = (int*)(ws + 43 * MB);       // 2 MB, dead after buildB_k
  float* adjw   = (float*)(ws + 45 * MB);     // 2 MB, dead after buildB_k
  int*   cnt    = (int*)(ws + 47 * MB);
  int*   rowptr = (int*)(ws + 47 * MB + 64 * 1024);
  int*   cursor = (int*)(ws + 47 * MB + 128 * 1024);
  float* scal   = (float*)(ws + 47 * MB + 256 * 1024);
  // 11 K x K split slots [0, 22M) over bitmap/pmatT (dead before first slot write)
  float* SL[11];
  for (int i = 0; i < 11; ++i) SL[i] = (float*)(ws + (size_t)i * SLOT);
  float *Xa = SL[0], *Ra = SL[1], *Ya = SL[2], *Za = SL[3];
  float *Xb = SL[4], *Rb = SL[5], *Yb = SL[6], *Zb = SL[7];
  float *Pm = SL[8], *S0h = SL[9], *TMP = SL[10];

  hipMemsetAsync(bitmap, 0, (size_t)VN * VN / 8, stream);
  hipMemsetAsync(cnt, 0, (size_t)VN * 4, stream);
  hipMemsetAsync(scal, 0, 64 * 4, stream);

  // stage A: graph construction -> L_adj (fp32, PSD-safe)
  transpose_k<<<dim3(VN / 32, KD / 32), 256, 0, stream>>>(pmat, pmatT);
  count_k<<<EN / 4, 256, 0, stream>>>(x, ei, ea, eb, ew, cnt, bitmap);
  scan_k<<<1, 1024, 0, stream>>>(cnt, rowptr, cursor);
  fill_k<<<EN / 256, 256, 0, stream>>>(ea, eb, ew, cursor, adjj, adjw);
  buildB_k<<<VN, 512, 0, stream>>>(pmatT, rowptr, adjj, adjw, Bm);
  setid_const_k<<<KK / 256, 256, 0, stream>>>(Ladj, 1e-5f);
  gemm_big_k<<<dim3(16, 16, 8), 256, 0, stream>>>(pmat, Bm, Ladj);

  // stage B prep: residual-form inverse NS
  sumsq_k<<<256, 256, 0, stream>>>(Ladj, KK, &scal[S_SS_LADJ]);
  derive_k<<<1, 1, 0, stream>>>(&scal[S_SS_LADJ], &scal[S_INV_C1], nullptr);
  initinv_split_k<<<KK / 256, 256, 0, stream>>>(Ladj, &scal[S_INV_C1], Xa, Ra);

  // stage C prep: coupled sqrt NS on S0/||S0||_F
  sumsq_k<<<256, 256, 0, stream>>>(S0, KK, &scal[S_SS_S0]);
  derive_k<<<1, 1, 0, stream>>>(&scal[S_SS_S0], &scal[S_INV_C0], &scal[S_QRT_C0]);
  scale_split_k<<<KK / 256, 256, 0, stream>>>(S0, &scal[S_INV_C0], Ya);
  setid_split_k<<<KK / 256, 256, 0, stream>>>(Za, 1.0f);

  // MFMA: 15 packed rounds (inv 15, sqrtS0 15)
  for (int r = 0; r < 15; ++r) {
    bc3_k<<<dim3(8, 8, 3), 256, 0, stream>>>(Za, Ya, Pm, Xa, Ra, Xb, Rb);
    yz2_k<<<dim3(8, 8, 2), 256, 0, stream>>>(Ya, Za, Pm, Yb, Zb);
    float* t = Xa; Xa = Xb; Xb = t;
    t = Ra; Ra = Rb; Rb = t;
    t = Ya; Ya = Yb; Yb = t;
    t = Za; Za = Zb; Zb = t;
  }

  // inverse polish: one classic Newton step in fp32 (quadratic contraction)
  float* U32  = Xb;
  float* Xfin = Rb;
  gemm_kk<<<dim3(16, 16), 256, 0, stream>>>(Ladj, Xa, nullptr, U32, 1.0f, 0.0f);
  gemm_kk<<<dim3(16, 16), 256, 0, stream>>>(Xa, U32, Xa, Xfin, -1.0f, 2.0f);
  trace_k<<<1, 512, 0, stream>>>(Xfin, &scal[S_TR_X]);
  trace_k<<<1, 512, 0, stream>>>(S0, &scal[S_TR_S0]);

  // sqrt(S0) polish: one fp32 NS Y-half-iteration (stable recurrence), then S0h = q0*Y
  gemm_kk<<<dim3(16, 16), 256, 0, stream>>>(Za, Ya, nullptr, Pm, 1.0f, 0.0f);
  gemm_kk<<<dim3(16, 16), 256, 0, stream>>>(Ya, Pm, Ya, Yb, -0.5f, 1.5f);
  scale32_k<<<KK / 256, 256, 0, stream>>>(Yb, &scal[S_QRT_C0], S0h);

  // stage D: G = S0h @ S1 @ S0h in fp32
  gemm_kk<<<dim3(16, 16), 256, 0, stream>>>(S0h, Xfin, nullptr, TMP, 1.0f, 0.0f);
  gemm_kk<<<dim3(16, 16), 256, 0, stream>>>(TMP, S0h, nullptr, Gs, 1.0f, 0.0f);
  sym_k<<<KK / 256, 256, 0, stream>>>(Gs, TMP);   // TMP = sym(G), fp32
  sumsq_k<<<256, 256, 0, stream>>>(TMP, KK, &scal[S_SS_G]);
  derive_k<<<1, 1, 0, stream>>>(&scal[S_SS_G], &scal[S_INV_CG], &scal[S_QRT_CG]);
  scale_split_k<<<KK / 256, 256, 0, stream>>>(TMP, &scal[S_INV_CG], Ya);
  setid_split_k<<<KK / 256, 256, 0, stream>>>(Za, 1.0f);
  // MFMA sqrt(G): 20 rounds
  for (int r = 0; r < 20; ++r) {
    pm1_k<<<dim3(8, 8, 1), 256, 0, stream>>>(Za, Ya, Pm);
    yz2_k<<<dim3(8, 8, 2), 256, 0, stream>>>(Ya, Za, Pm, Yb, Zb);
    float* t = Ya; Ya = Yb; Yb = t;
    t = Za; Za = Zb; Zb = t;
  }
  // sqrt(G) polish: two fp32 NS iterations (damps MFMA noise 0.25x + 2 doublings)
  gemm_kk<<<dim3(16, 16), 256, 0, stream>>>(Za, Ya, nullptr, Pm, 1.0f, 0.0f);
  gemm_dual32<<<dim3(16, 16, 2), 256, 0, stream>>>(Ya, Pm, Ya, Yb,
                                                   Pm, Za, Za, Zb, -0.5f, 1.5f);
  gemm_kk<<<dim3(16, 16), 256, 0, stream>>>(Zb, Yb, nullptr, Pm, 1.0f, 0.0f);
  gemm_kk<<<dim3(16, 16), 256, 0, stream>>>(Yb, Pm, Yb, S0h, -0.5f, 1.5f);  // S0h = Y_final
  trace_k<<<1, 512, 0, stream>>>(S0h, &scal[S_TR_YG]);

  final_k<<<1, 1, 0, stream>>>(scal, out);
}

// Round 13
// 1466.137 us; speedup vs baseline: 4.8780x; 1.0776x over previous
//
#include <hip/hip_runtime.h>
#include <math.h>

#define VN 8192
#define DN 128
#define EN 262144
#define KD 512
#define KK (KD*KD)

// scalar slots
#define S_SS_LADJ 0
#define S_INV_C1  1
#define S_SS_S0   2
#define S_INV_C0  3
#define S_QRT_C0  4
#define S_SS_G    5
#define S_INV_CG  6
#define S_QRT_CG  7
#define S_TR_X    8
#define S_TR_S0   9
#define S_TR_YG   10

typedef __attribute__((ext_vector_type(8))) __bf16 bf16x8;
typedef __attribute__((ext_vector_type(4))) float f32x4;

static __device__ __forceinline__ float waveReduceAdd(float v) {
#pragma unroll
  for (int o = 32; o; o >>= 1) v += __shfl_xor(v, o);
  return v;
}

static __device__ __forceinline__ ushort f2b(float f) {
  unsigned x = __float_as_uint(f);
  unsigned r = (x + 0x7fffu + ((x >> 16) & 1u)) >> 16;
  return (ushort)r;
}
static __device__ __forceinline__ float b2f(ushort u) {
  return __uint_as_float((unsigned)u << 16);
}

// ---------- stage A: graph -> L_adj (fp32, proven path) ----------

__global__ __launch_bounds__(256) void transpose_k(const float* __restrict__ in,
                                                   float* __restrict__ out) {
  __shared__ float s[32][33];
  int tx = threadIdx.x & 31, ty = threadIdx.x >> 5;
  int v0 = blockIdx.x * 32, k0 = blockIdx.y * 32;
  for (int r = ty; r < 32; r += 8) s[r][tx] = in[(size_t)(k0 + r) * VN + v0 + tx];
  __syncthreads();
  for (int r = ty; r < 32; r += 8) out[(size_t)(v0 + r) * KD + k0 + tx] = s[tx][r];
}

// 4 edges per wave (16-lane groups), float4 distance loads
__global__ __launch_bounds__(256) void count_k(const float* __restrict__ x,
                                               const int* __restrict__ ei,
                                               int* __restrict__ ea, int* __restrict__ eb,
                                               float* __restrict__ ew,
                                               int* __restrict__ cnt,
                                               unsigned int* __restrict__ bitmap) {
  int e = (int)(((unsigned)blockIdx.x * 256u + threadIdx.x) >> 4);
  int lane = threadIdx.x & 63;
  int sl = lane & 15;
  if (e >= EN) return;
  int i = ei[e], j = ei[EN + e];
  int a = i < j ? i : j;
  int b = i < j ? j : i;
  int ok = 0;
  if (sl == 0) {
    if (i != j) {
      unsigned key = (unsigned)a * (unsigned)VN + (unsigned)b;
      unsigned m = 1u << (key & 31u);
      unsigned old = atomicOr(bitmap + (key >> 5), m);
      ok = (old & m) ? 0 : 1;
    }
  }
  ok = __shfl(ok, lane & 48);  // broadcast from group leader
  if (!ok) { if (sl == 0) ea[e] = -1; return; }
  const float4* xa = (const float4*)&x[(size_t)a * DN + sl * 8];
  const float4* xb = (const float4*)&x[(size_t)b * DN + sl * 8];
  float4 a0 = xa[0], a1 = xa[1], b0 = xb[0], b1 = xb[1];
  float d0 = a0.x - b0.x, d1 = a0.y - b0.y, d2 = a0.z - b0.z, d3 = a0.w - b0.w;
  float d4 = a1.x - b1.x, d5 = a1.y - b1.y, d6 = a1.z - b1.z, d7 = a1.w - b1.w;
  float s = d0*d0 + d1*d1 + d2*d2 + d3*d3 + d4*d4 + d5*d5 + d6*d6 + d7*d7;
#pragma unroll
  for (int o = 8; o; o >>= 1) s += __shfl_xor(s, o);
  if (sl == 0) {
    ea[e] = a; eb[e] = b; ew[e] = expf(-s);
    atomicAdd(cnt + a, 1);
    atomicAdd(cnt + b, 1);
  }
}

__global__ __launch_bounds__(1024) void scan_k(const int* __restrict__ cnt,
                                               int* __restrict__ rowptr,
                                               int* __restrict__ cursor) {
  __shared__ int sd[1024];
  __shared__ int carry;
  int tid = threadIdx.x;
  if (tid == 0) { carry = 0; rowptr[0] = 0; }
  __syncthreads();
  for (int c = 0; c < VN / 1024; ++c) {
    int v = c * 1024 + tid;
    int xv = cnt[v];
    sd[tid] = xv;
    __syncthreads();
    for (int off = 1; off < 1024; off <<= 1) {
      int t = (tid >= off) ? sd[tid - off] : 0;
      __syncthreads();
      sd[tid] += t;
      __syncthreads();
    }
    int incl = sd[tid];
    int base = carry;
    rowptr[v + 1] = base + incl;
    cursor[v] = base + incl - xv;
    __syncthreads();
    if (tid == 1023) carry = base + incl;
    __syncthreads();
  }
}

__global__ __launch_bounds__(256) void fill_k(const int* __restrict__ ea, const int* __restrict__ eb,
                                              const float* __restrict__ ew,
                                              int* __restrict__ cursor,
                                              int* __restrict__ adjj, float* __restrict__ adjw) {
  int e = blockIdx.x * 256 + threadIdx.x;
  if (e >= EN) return;
  int a = ea[e];
  if (a < 0) return;
  int b = eb[e];
  float w = ew[e];
  int p = atomicAdd(cursor + a, 1); adjj[p] = b; adjw[p] = w;
  int q = atomicAdd(cursor + b, 1); adjj[q] = a; adjw[q] = w;
}

__global__ __launch_bounds__(512) void buildB_k(const float* __restrict__ pmatT,
                                                const int* __restrict__ rowptr,
                                                const int* __restrict__ adjj,
                                                const float* __restrict__ adjw,
                                                float* __restrict__ Bout) {
  int v = blockIdx.x;
  int k = threadIdx.x;
  int s = rowptr[v], e = rowptr[v + 1];
  float a0 = 0.f, a1 = 0.f, a2 = 0.f, a3 = 0.f, sw = 0.f;
  int p = s;
  for (; p + 4 <= e; p += 4) {
    int j0 = adjj[p], j1 = adjj[p + 1], j2 = adjj[p + 2], j3 = adjj[p + 3];
    float w0 = adjw[p], w1 = adjw[p + 1], w2 = adjw[p + 2], w3 = adjw[p + 3];
    a0 += w0 * pmatT[(size_t)j0 * KD + k];
    a1 += w1 * pmatT[(size_t)j1 * KD + k];
    a2 += w2 * pmatT[(size_t)j2 * KD + k];
    a3 += w3 * pmatT[(size_t)j3 * KD + k];
    sw += w0 + w1 + w2 + w3;
  }
  for (; p < e; ++p) {
    int jj = adjj[p];
    float w = adjw[p];
    a0 += w * pmatT[(size_t)jj * KD + k];
    sw += w;
  }
  Bout[(size_t)v * KD + k] = sw * pmatT[(size_t)v * KD + k] - (a0 + a1 + a2 + a3);
}

// Ladj(512x512) += pmat(512x8192) @ Bm(8192x512): 64x64 tile, 4x4/thread, split-K=8
__global__ __launch_bounds__(256) void gemm_big_k(const float* __restrict__ A,
                                                  const float* __restrict__ B,
                                                  float* __restrict__ C) {
  __shared__ __align__(16) float As[32][68];
  __shared__ __align__(16) float Bs[32][68];
  int tid = threadIdx.x;
  int tx = tid & 15, ty = tid >> 4;
  int n0 = blockIdx.x * 64, m0 = blockIdx.y * 64;
  int kbase = blockIdx.z * (VN / 8);
  float acc[4][4] = {};
  for (int kt = kbase; kt < kbase + VN / 8; kt += 32) {
    // stage A 64x32 (transposed into As[k][row]) and B 32x64 (Bs[k][col])
#pragma unroll
    for (int u = 0; u < 2; ++u) {
      int li = tid * 2 + u;                 // 0..511
      int r = li >> 3, c = (li & 7) * 4;    // A: row 0..63, k-chunk
      float4 av = *(const float4*)&A[(size_t)(m0 + r) * VN + kt + c];
      As[c][r] = av.x; As[c + 1][r] = av.y; As[c + 2][r] = av.z; As[c + 3][r] = av.w;
      int rb = li >> 4, cb = (li & 15) * 4; // B: k 0..31, col-chunk
      *(float4*)&Bs[rb][cb] = *(const float4*)&B[(size_t)(kt + rb) * KD + n0 + cb];
    }
    __syncthreads();
#pragma unroll
    for (int k = 0; k < 32; ++k) {
      float4 av = *(const float4*)&As[k][ty * 4];
      float4 bv = *(const float4*)&Bs[k][tx * 4];
      float am[4] = {av.x, av.y, av.z, av.w};
      float bm[4] = {bv.x, bv.y, bv.z, bv.w};
#pragma unroll
      for (int mi = 0; mi < 4; ++mi)
#pragma unroll
        for (int ni = 0; ni < 4; ++ni) acc[mi][ni] += am[mi] * bm[ni];
    }
    __syncthreads();
  }
#pragma unroll
  for (int mi = 0; mi < 4; ++mi)
#pragma unroll
    for (int ni = 0; ni < 4; ++ni)
      atomicAdd(&C[(m0 + ty * 4 + mi) * KD + n0 + tx * 4 + ni], acc[mi][ni]);
}

// ---------- fp32 K x K GEMM (round-1 proven body) ----------

static __device__ __forceinline__ void g32_body(const float* __restrict__ A,
                                                const float* __restrict__ B,
                                                const float* __restrict__ Dm,
                                                float* __restrict__ C,
                                                float alpha, float beta) {
  __shared__ __align__(16) float As[32][34];
  __shared__ __align__(16) float Bs[32][34];
  int tid = threadIdx.x;
  int tx = tid & 15, ty = tid >> 4;
  int n0 = blockIdx.x * 32, m0 = blockIdx.y * 32;
  float a00 = 0.f, a01 = 0.f, a10 = 0.f, a11 = 0.f;
  for (int kt = 0; kt < KD; kt += 32) {
#pragma unroll
    for (int u = 0; u < 4; ++u) {
      int li = tid * 4 + u;
      int r = li >> 5, c = li & 31;
      As[c][r] = A[(m0 + r) * KD + kt + c];
      Bs[r][c] = B[(kt + r) * KD + n0 + c];
    }
    __syncthreads();
#pragma unroll
    for (int k = 0; k < 32; ++k) {
      float2 av = *(const float2*)&As[k][2 * ty];
      float2 bv = *(const float2*)&Bs[k][2 * tx];
      a00 += av.x * bv.x; a01 += av.x * bv.y;
      a10 += av.y * bv.x; a11 += av.y * bv.y;
    }
    __syncthreads();
  }
  int m = m0 + 2 * ty, n = n0 + 2 * tx;
  float d00 = 0.f, d01 = 0.f, d10 = 0.f, d11 = 0.f;
  if (beta != 0.0f) {
    d00 = Dm[m * KD + n];       d01 = Dm[m * KD + n + 1];
    d10 = Dm[(m + 1) * KD + n]; d11 = Dm[(m + 1) * KD + n + 1];
  }
  C[m * KD + n]           = alpha * a00 + beta * d00;
  C[m * KD + n + 1]       = alpha * a01 + beta * d01;
  C[(m + 1) * KD + n]     = alpha * a10 + beta * d10;
  C[(m + 1) * KD + n + 1] = alpha * a11 + beta * d11;
}

__global__ __launch_bounds__(256) void gemm_kk(const float* __restrict__ A,
                                               const float* __restrict__ B,
                                               const float* __restrict__ Dm,
                                               float* __restrict__ C,
                                               float alpha, float beta) {
  g32_body(A, B, Dm, C, alpha, beta);
}

// two independent fp32 GEMMs, per-z alpha/beta
__global__ __launch_bounds__(256) void gemm_dual32(const float* A0, const float* B0,
                                                   const float* D0, float* C0,
                                                   float alpha0, float beta0,
                                                   const float* A1, const float* B1,
                                                   const float* D1, float* C1,
                                                   float alpha1, float beta1) {
  if (blockIdx.z == 0) g32_body(A0, B0, D0, C0, alpha0, beta0);
  else                 g32_body(A1, B1, D1, C1, alpha1, beta1);
}

// ---------- 2-way-split bf16 MFMA K x K GEMM (round-6 proven, 3 terms) ----------

struct SmemT { ushort a[2][64][40]; ushort b[2][64][40]; };  // 20480 B

static __device__ __forceinline__ void mgemm_s(SmemT* sm,
    const float* Asl, const float* Bsl, const float* Dsl, float* Csl,
    float alpha, float beta, int wsplit) {
  const ushort* Ah = (const ushort*)(Asl + KK);
  const ushort* Al = Ah + KK;
  const ushort* Bh = (const ushort*)(Bsl + KK);
  const ushort* Bl = Bh + KK;
  int tid = threadIdx.x;
  int lane = tid & 63, wave = tid >> 6;
  int wr = wave >> 1, wc = wave & 1;
  int fr = lane & 15, fq = lane >> 4;
  int m0 = blockIdx.y * 64, n0 = blockIdx.x * 64;
  int sr = tid >> 2, skc = (tid & 3) * 8;
  f32x4 acc[2][2] = {};
  for (int kt = 0; kt < KD; kt += 32) {
    *(uint4*)&sm->a[0][sr][skc] = *(const uint4*)&Ah[(size_t)(m0 + sr) * KD + kt + skc];
    *(uint4*)&sm->a[1][sr][skc] = *(const uint4*)&Al[(size_t)(m0 + sr) * KD + kt + skc];
    *(uint4*)&sm->b[0][sr][skc] = *(const uint4*)&Bh[(size_t)(n0 + sr) * KD + kt + skc];
    *(uint4*)&sm->b[1][sr][skc] = *(const uint4*)&Bl[(size_t)(n0 + sr) * KD + kt + skc];
    __syncthreads();
    bf16x8 ah[2], al[2], bh[2], bl[2];
#pragma unroll
    for (int m = 0; m < 2; ++m) {
      ah[m] = *(const bf16x8*)&sm->a[0][wr * 32 + m * 16 + fr][fq * 8];
      al[m] = *(const bf16x8*)&sm->a[1][wr * 32 + m * 16 + fr][fq * 8];
    }
#pragma unroll
    for (int n = 0; n < 2; ++n) {
      bh[n] = *(const bf16x8*)&sm->b[0][wc * 32 + n * 16 + fr][fq * 8];
      bl[n] = *(const bf16x8*)&sm->b[1][wc * 32 + n * 16 + fr][fq * 8];
    }
#pragma unroll
    for (int m = 0; m < 2; ++m)
#pragma unroll
      for (int n = 0; n < 2; ++n) {
        acc[m][n] = __builtin_amdgcn_mfma_f32_16x16x32_bf16(ah[m], bh[n], acc[m][n], 0, 0, 0);
        acc[m][n] = __builtin_amdgcn_mfma_f32_16x16x32_bf16(ah[m], bl[n], acc[m][n], 0, 0, 0);
        acc[m][n] = __builtin_amdgcn_mfma_f32_16x16x32_bf16(al[m], bh[n], acc[m][n], 0, 0, 0);
      }
    __syncthreads();
  }
  ushort* Ch = (ushort*)(Csl + KK);
  ushort* Cl = Ch + KK;
#pragma unroll
  for (int m = 0; m < 2; ++m)
#pragma unroll
    for (int n = 0; n < 2; ++n) {
      int col = n0 + wc * 32 + n * 16 + fr;
#pragma unroll
      for (int j = 0; j < 4; ++j) {
        int row = m0 + wr * 32 + m * 16 + fq * 4 + j;
        float v = alpha * acc[m][n][j];
        if (beta != 0.f) v += beta * Dsl[row * KD + col];
        Csl[row * KD + col] = v;
        if (wsplit) {
          ushort h = f2b(v);
          Ch[row * KD + col] = h;
          Cl[row * KD + col] = f2b(v - b2f(h));
        }
      }
    }
}

__global__ __launch_bounds__(256) void bc3_k(const float* Za, const float* Ya, float* Pm,
                                             const float* Xa, const float* Ra,
                                             float* Xb, float* Rb) {
  __shared__ SmemT sm;
  int z = blockIdx.z;
  if (z == 0)      mgemm_s(&sm, Za, Ya, nullptr, Pm, 1.f, 0.f, 1);
  else if (z == 1) mgemm_s(&sm, Xa, Ra, Xa, Xb, 1.f, 1.f, 1);
  else             mgemm_s(&sm, Ra, Ra, nullptr, Rb, 1.f, 0.f, 1);
}

__global__ __launch_bounds__(256) void yz2_k(const float* Ya, const float* Za, const float* Pm,
                                             float* Yb, float* Zb) {
  __shared__ SmemT sm;
  if (blockIdx.z == 0) mgemm_s(&sm, Ya, Pm, Ya, Yb, -0.5f, 1.5f, 1);
  else                 mgemm_s(&sm, Pm, Za, Za, Zb, -0.5f, 1.5f, 1);
}

__global__ __launch_bounds__(256) void pm1_k(const float* Za, const float* Ya, float* Pm) {
  __shared__ SmemT sm;
  mgemm_s(&sm, Za, Ya, nullptr, Pm, 1.f, 0.f, 1);
}

// ---------- small utility kernels ----------

__global__ __launch_bounds__(256) void sumsq_k(const float* __restrict__ A, int n,
                                               float* __restrict__ slot) {
  float s = 0.f;
  for (int i = blockIdx.x * 256 + threadIdx.x; i < n; i += gridDim.x * 256) {
    float v = A[i];
    s += v * v;
  }
  __shared__ float p[4];
  s = waveReduceAdd(s);
  if ((threadIdx.x & 63) == 0) p[threadIdx.x >> 6] = s;
  __syncthreads();
  if (threadIdx.x == 0) atomicAdd(slot, p[0] + p[1] + p[2] + p[3]);
}

__global__ __launch_bounds__(512) void trace_k(const float* __restrict__ A,
                                               float* __restrict__ slot) {
  float v = A[(size_t)threadIdx.x * KD + threadIdx.x];
  __shared__ float p[8];
  v = waveReduceAdd(v);
  if ((threadIdx.x & 63) == 0) p[threadIdx.x >> 6] = v;
  __syncthreads();
  if (threadIdx.x == 0) {
    float t = 0.f;
    for (int i = 0; i < 8; ++i) t += p[i];
    slot[0] = t;
  }
}

// two traces in one launch (z picks matrix/slot)
__global__ __launch_bounds__(512) void trace2_k(const float* __restrict__ A0, float* s0,
                                                const float* __restrict__ A1, float* s1) {
  const float* A = blockIdx.z ? A1 : A0;
  float* slot = blockIdx.z ? s1 : s0;
  float v = A[(size_t)threadIdx.x * KD + threadIdx.x];
  __shared__ float p[8];
  v = waveReduceAdd(v);
  if ((threadIdx.x & 63) == 0) p[threadIdx.x >> 6] = v;
  __syncthreads();
  if (threadIdx.x == 0) {
    float t = 0.f;
    for (int i = 0; i < 8; ++i) t += p[i];
    slot[0] = t;
  }
}

__global__ void derive_k(const float* __restrict__ in, float* __restrict__ o_rsqrt,
                         float* __restrict__ o_qroot) {
  float x = in[0];
  o_rsqrt[0] = 1.0f / sqrtf(x);
  if (o_qroot) o_qroot[0] = powf(x, 0.25f);
}

__global__ __launch_bounds__(256) void setid_const_k(float* __restrict__ C, float val) {
  int idx = blockIdx.x * 256 + threadIdx.x;
  int r = idx >> 9, c = idx & (KD - 1);
  C[idx] = (r == c) ? val : 0.0f;
}

__global__ __launch_bounds__(256) void initinv_split_k(const float* __restrict__ Ladj,
                                                       const float* __restrict__ s,
                                                       float* __restrict__ X,
                                                       float* __restrict__ R) {
  int idx = blockIdx.x * 256 + threadIdx.x;
  int r = idx >> 9, c = idx & (KD - 1);
  float cv = s[0];
  float id = (r == c) ? 1.f : 0.f;
  float xv = id * cv;
  float rv = id - cv * Ladj[idx];
  ushort* Xh = (ushort*)(X + KK); ushort* Xl = Xh + KK;
  ushort* Rh = (ushort*)(R + KK); ushort* Rl = Rh + KK;
  X[idx] = xv; ushort h = f2b(xv); Xh[idx] = h; Xl[idx] = f2b(xv - b2f(h));
  R[idx] = rv; h = f2b(rv);        Rh[idx] = h; Rl[idx] = f2b(rv - b2f(h));
}

__global__ __launch_bounds__(256) void setid_split_k(float* __restrict__ C, float val) {
  int idx = blockIdx.x * 256 + threadIdx.x;
  int r = idx >> 9, c = idx & (KD - 1);
  float v = (r == c) ? val : 0.0f;
  ushort* Chh = (ushort*)(C + KK); ushort* Cll = Chh + KK;
  C[idx] = v; ushort h = f2b(v); Chh[idx] = h; Cll[idx] = f2b(v - b2f(h));
}

__global__ __launch_bounds__(256) void scale_split_k(const float* __restrict__ A,
                                                     const float* __restrict__ s,
                                                     float* __restrict__ C) {
  int idx = blockIdx.x * 256 + threadIdx.x;
  float v = A[idx] * s[0];
  ushort* Chh = (ushort*)(C + KK); ushort* Cll = Chh + KK;
  C[idx] = v; ushort h = f2b(v); Chh[idx] = h; Cll[idx] = f2b(v - b2f(h));
}

__global__ __launch_bounds__(256) void scale32_k(const float* __restrict__ A,
                                                 const float* __restrict__ s,
                                                 float* __restrict__ C) {
  int idx = blockIdx.x * 256 + threadIdx.x;
  C[idx] = A[idx] * s[0];
}

__global__ __launch_bounds__(256) void sym_k(const float* __restrict__ G,
                                             float* __restrict__ Out) {
  int idx = blockIdx.x * 256 + threadIdx.x;
  int r = idx >> 9, c = idx & (KD - 1);
  Out[idx] = 0.5f * (G[idx] + G[c * KD + r]);
}

__global__ void final_k(const float* __restrict__ scal, float* __restrict__ out) {
  out[0] = scal[S_TR_X] + scal[S_TR_S0] - 2.0f * scal[S_QRT_CG] * scal[S_TR_YG];
}

// ---------- host ----------

extern "C" void kernel_launch(void* const* d_in, const int* in_sizes, int n_in,
                              void* d_out, int out_size, void* d_ws, size_t ws_size,
                              hipStream_t stream) {
  (void)in_sizes; (void)n_in; (void)out_size; (void)ws_size;
  const float* x    = (const float*)d_in[0];  // V x D
  const float* S0   = (const float*)d_in[1];  // K x K
  const int*   ei   = (const int*)d_in[2];    // 2 x E
  const float* pmat = (const float*)d_in[3];  // K x V
  float* out = (float*)d_out;
  char* ws = (char*)d_ws;
  const size_t MB = 1u << 20;
  const size_t SLOT = 2 * MB;  // f32 + h + l

  unsigned* bitmap = (unsigned*)ws;           // [0,8M), dead after count_k
  float* pmatT = (float*)(ws + 8 * MB);       // [8,24M), dead after buildB_k
  float* Bm    = (float*)(ws + 24 * MB);      // [24,40M), dead after gemm_big_k
  float* Ladj  = (float*)(ws + 40 * MB);      // over ea (dead after fill_k); alive to inv polish
  float* Gs    = (float*)(ws + 41 * MB);      // over eb (dead after fill_k); stage D
  int*   ea     = (int*)(ws + 40 * MB);       // dead after fill_k
  int*   eb     = (int*)(ws + 41 * MB);       // dead after fill_k
  float* ew     = (float*)(ws + 42 * MB);     // dead after fill_k
  int*   adjj   = (int*)(ws + 43 * MB);       // 2 MB, dead after buildB_k
  float* adjw   = (float*)(ws + 45 * MB);     // 2 MB, dead after buildB_k
  int*   cnt    = (int*)(ws + 47 * MB);
  int*   rowptr = (int*)(ws + 47 * MB + 64 * 1024);
  int*   cursor = (int*)(ws + 47 * MB + 128 * 1024);
  float* scal   = (float*)(ws + 47 * MB + 256 * 1024);
  float* SL[11];
  for (int i = 0; i < 11; ++i) SL[i] = (float*)(ws + (size_t)i * SLOT);
  float *Xa = SL[0], *Ra = SL[1], *Ya = SL[2], *Za = SL[3];
  float *Xb = SL[4], *Rb = SL[5], *Yb = SL[6], *Zb = SL[7];
  float *Pm = SL[8], *S0h = SL[9], *TMP = SL[10];

  hipMemsetAsync(bitmap, 0, (size_t)VN * VN / 8, stream);
  hipMemsetAsync(cnt, 0, (size_t)VN * 4, stream);
  hipMemsetAsync(scal, 0, 64 * 4, stream);

  // stage A: graph construction -> L_adj (fp32, PSD-safe)
  transpose_k<<<dim3(VN / 32, KD / 32), 256, 0, stream>>>(pmat, pmatT);
  count_k<<<EN / 16, 256, 0, stream>>>(x, ei, ea, eb, ew, cnt, bitmap);
  scan_k<<<1, 1024, 0, stream>>>(cnt, rowptr, cursor);
  fill_k<<<EN / 256, 256, 0, stream>>>(ea, eb, ew, cursor, adjj, adjw);
  buildB_k<<<VN, 512, 0, stream>>>(pmatT, rowptr, adjj, adjw, Bm);
  setid_const_k<<<KK / 256, 256, 0, stream>>>(Ladj, 1e-5f);
  gemm_big_k<<<dim3(8, 8, 8), 256, 0, stream>>>(pmat, Bm, Ladj);

  // stage B prep: residual-form inverse NS
  sumsq_k<<<256, 256, 0, stream>>>(Ladj, KK, &scal[S_SS_LADJ]);
  derive_k<<<1, 1, 0, stream>>>(&scal[S_SS_LADJ], &scal[S_INV_C1], nullptr);
  initinv_split_k<<<KK / 256, 256, 0, stream>>>(Ladj, &scal[S_INV_C1], Xa, Ra);

  // stage C prep: coupled sqrt NS on S0/||S0||_F
  sumsq_k<<<256, 256, 0, stream>>>(S0, KK, &scal[S_SS_S0]);
  derive_k<<<1, 1, 0, stream>>>(&scal[S_SS_S0], &scal[S_INV_C0], &scal[S_QRT_C0]);
  scale_split_k<<<KK / 256, 256, 0, stream>>>(S0, &scal[S_INV_C0], Ya);
  setid_split_k<<<KK / 256, 256, 0, stream>>>(Za, 1.0f);

  // MFMA: 15 packed rounds (inv 15, sqrtS0 15)
  for (int r = 0; r < 15; ++r) {
    bc3_k<<<dim3(8, 8, 3), 256, 0, stream>>>(Za, Ya, Pm, Xa, Ra, Xb, Rb);
    yz2_k<<<dim3(8, 8, 2), 256, 0, stream>>>(Ya, Za, Pm, Yb, Zb);
    float* t = Xa; Xa = Xb; Xb = t;
    t = Ra; Ra = Rb; Rb = t;
    t = Ya; Ya = Yb; Yb = t;
    t = Za; Za = Zb; Zb = t;
  }

  // packed polish L1: {U32 = Ladj@Xa} || {Pm = Za@Ya}   (independent chains)
  float* U32  = Xb;
  float* Xfin = Rb;
  gemm_dual32<<<dim3(16, 16, 2), 256, 0, stream>>>(Ladj, Xa, nullptr, U32, 1.0f, 0.0f,
                                                   Za, Ya, nullptr, Pm, 1.0f, 0.0f);
  // packed polish L2: {Xfin = 2Xa - Xa@U32} || {Yb = 1.5Ya - 0.5 Ya@Pm}
  gemm_dual32<<<dim3(16, 16, 2), 256, 0, stream>>>(Xa, U32, Xa, Xfin, -1.0f, 2.0f,
                                                   Ya, Pm, Ya, Yb, -0.5f, 1.5f);
  trace2_k<<<dim3(1, 1, 2), 512, 0, stream>>>(Xfin, &scal[S_TR_X], S0, &scal[S_TR_S0]);
  scale32_k<<<KK / 256, 256, 0, stream>>>(Yb, &scal[S_QRT_C0], S0h);

  // stage D: G = S0h @ S1 @ S0h in fp32
  gemm_kk<<<dim3(16, 16), 256, 0, stream>>>(S0h, Xfin, nullptr, TMP, 1.0f, 0.0f);
  gemm_kk<<<dim3(16, 16), 256, 0, stream>>>(TMP, S0h, nullptr, Gs, 1.0f, 0.0f);
  sym_k<<<KK / 256, 256, 0, stream>>>(Gs, TMP);   // TMP = sym(G), fp32
  sumsq_k<<<256, 256, 0, stream>>>(TMP, KK, &scal[S_SS_G]);
  derive_k<<<1, 1, 0, stream>>>(&scal[S_SS_G], &scal[S_INV_CG], &scal[S_QRT_CG]);
  scale_split_k<<<KK / 256, 256, 0, stream>>>(TMP, &scal[S_INV_CG], Ya);
  setid_split_k<<<KK / 256, 256, 0, stream>>>(Za, 1.0f);
  // MFMA sqrt(G): 20 rounds
  for (int r = 0; r < 20; ++r) {
    pm1_k<<<dim3(8, 8, 1), 256, 0, stream>>>(Za, Ya, Pm);
    yz2_k<<<dim3(8, 8, 2), 256, 0, stream>>>(Ya, Za, Pm, Yb, Zb);
    float* t = Ya; Ya = Yb; Yb = t;
    t = Za; Za = Zb; Zb = t;
  }
  // sqrt(G) polish: two fp32 NS iterations
  gemm_kk<<<dim3(16, 16), 256, 0, stream>>>(Za, Ya, nullptr, Pm, 1.0f, 0.0f);
  gemm_dual32<<<dim3(16, 16, 2), 256, 0, stream>>>(Ya, Pm, Ya, Yb, -0.5f, 1.5f,
                                                   Pm, Za, Za, Zb, -0.5f, 1.5f);
  gemm_kk<<<dim3(16, 16), 256, 0, stream>>>(Zb, Yb, nullptr, Pm, 1.0f, 0.0f);
  gemm_kk<<<dim3(16, 16), 256, 0, stream>>>(Yb, Pm, Yb, S0h, -0.5f, 1.5f);  // S0h = Y_final
  trace_k<<<1, 512, 0, stream>>>(S0h, &scal[S_TR_YG]);

  final_k<<<1, 1, 0, stream>>>(scal, out);
}

// Round 14
// 1421.874 us; speedup vs baseline: 5.0298x; 1.0311x over previous
//
#include <hip/hip_runtime.h>
#include <math.h>

#define VN 8192
#define DN 128
#define EN 262144
#define KD 512
#define KK (KD*KD)

// scalar slots
#define S_SS_LADJ 0
#define S_INV_C1  1
#define S_SS_S0   2
#define S_INV_C0  3
#define S_QRT_C0  4
#define S_SS_G    5
#define S_INV_CG  6
#define S_QRT_CG  7
#define S_TR_X    8
#define S_TR_S0   9
#define S_TR_YG   10

typedef __attribute__((ext_vector_type(8))) __bf16 bf16x8;
typedef __attribute__((ext_vector_type(4))) float f32x4;

static __device__ __forceinline__ float waveReduceAdd(float v) {
#pragma unroll
  for (int o = 32; o; o >>= 1) v += __shfl_xor(v, o);
  return v;
}

static __device__ __forceinline__ ushort f2b(float f) {
  unsigned x = __float_as_uint(f);
  unsigned r = (x + 0x7fffu + ((x >> 16) & 1u)) >> 16;
  return (ushort)r;
}
static __device__ __forceinline__ float b2f(ushort u) {
  return __uint_as_float((unsigned)u << 16);
}

// ---------- stage A: graph -> L_adj (fp32, proven path) ----------

__global__ __launch_bounds__(256) void transpose_k(const float* __restrict__ in,
                                                   float* __restrict__ out) {
  __shared__ float s[32][33];
  int tx = threadIdx.x & 31, ty = threadIdx.x >> 5;
  int v0 = blockIdx.x * 32, k0 = blockIdx.y * 32;
  for (int r = ty; r < 32; r += 8) s[r][tx] = in[(size_t)(k0 + r) * VN + v0 + tx];
  __syncthreads();
  for (int r = ty; r < 32; r += 8) out[(size_t)(v0 + r) * KD + k0 + tx] = s[tx][r];
}

// 4 edges per wave (16-lane groups), float4 distance loads
__global__ __launch_bounds__(256) void count_k(const float* __restrict__ x,
                                               const int* __restrict__ ei,
                                               int* __restrict__ ea, int* __restrict__ eb,
                                               float* __restrict__ ew,
                                               int* __restrict__ cnt,
                                               unsigned int* __restrict__ bitmap) {
  int e = (int)(((unsigned)blockIdx.x * 256u + threadIdx.x) >> 4);
  int lane = threadIdx.x & 63;
  int sl = lane & 15;
  if (e >= EN) return;
  int i = ei[e], j = ei[EN + e];
  int a = i < j ? i : j;
  int b = i < j ? j : i;
  int ok = 0;
  if (sl == 0) {
    if (i != j) {
      unsigned key = (unsigned)a * (unsigned)VN + (unsigned)b;
      unsigned m = 1u << (key & 31u);
      unsigned old = atomicOr(bitmap + (key >> 5), m);
      ok = (old & m) ? 0 : 1;
    }
  }
  ok = __shfl(ok, lane & 48);  // broadcast from group leader
  if (!ok) { if (sl == 0) ea[e] = -1; return; }
  const float4* xa = (const float4*)&x[(size_t)a * DN + sl * 8];
  const float4* xb = (const float4*)&x[(size_t)b * DN + sl * 8];
  float4 a0 = xa[0], a1 = xa[1], b0 = xb[0], b1 = xb[1];
  float d0 = a0.x - b0.x, d1 = a0.y - b0.y, d2 = a0.z - b0.z, d3 = a0.w - b0.w;
  float d4 = a1.x - b1.x, d5 = a1.y - b1.y, d6 = a1.z - b1.z, d7 = a1.w - b1.w;
  float s = d0*d0 + d1*d1 + d2*d2 + d3*d3 + d4*d4 + d5*d5 + d6*d6 + d7*d7;
#pragma unroll
  for (int o = 8; o; o >>= 1) s += __shfl_xor(s, o);
  if (sl == 0) {
    ea[e] = a; eb[e] = b; ew[e] = expf(-s);
    atomicAdd(cnt + a, 1);
    atomicAdd(cnt + b, 1);
  }
}

__global__ __launch_bounds__(1024) void scan_k(const int* __restrict__ cnt,
                                               int* __restrict__ rowptr,
                                               int* __restrict__ cursor) {
  __shared__ int sd[1024];
  __shared__ int carry;
  int tid = threadIdx.x;
  if (tid == 0) { carry = 0; rowptr[0] = 0; }
  __syncthreads();
  for (int c = 0; c < VN / 1024; ++c) {
    int v = c * 1024 + tid;
    int xv = cnt[v];
    sd[tid] = xv;
    __syncthreads();
    for (int off = 1; off < 1024; off <<= 1) {
      int t = (tid >= off) ? sd[tid - off] : 0;
      __syncthreads();
      sd[tid] += t;
      __syncthreads();
    }
    int incl = sd[tid];
    int base = carry;
    rowptr[v + 1] = base + incl;
    cursor[v] = base + incl - xv;
    __syncthreads();
    if (tid == 1023) carry = base + incl;
    __syncthreads();
  }
}

__global__ __launch_bounds__(256) void fill_k(const int* __restrict__ ea, const int* __restrict__ eb,
                                              const float* __restrict__ ew,
                                              int* __restrict__ cursor,
                                              int* __restrict__ adjj, float* __restrict__ adjw) {
  int e = blockIdx.x * 256 + threadIdx.x;
  if (e >= EN) return;
  int a = ea[e];
  if (a < 0) return;
  int b = eb[e];
  float w = ew[e];
  int p = atomicAdd(cursor + a, 1); adjj[p] = b; adjw[p] = w;
  int q = atomicAdd(cursor + b, 1); adjj[q] = a; adjw[q] = w;
}

// one vertex per block, k = threadIdx; gather loop unrolled x8 (8 indep loads in flight)
__global__ __launch_bounds__(512) void buildB_k(const float* __restrict__ pmatT,
                                                const int* __restrict__ rowptr,
                                                const int* __restrict__ adjj,
                                                const float* __restrict__ adjw,
                                                float* __restrict__ Bout) {
  int v = blockIdx.x;
  int k = threadIdx.x;
  int s = rowptr[v], e = rowptr[v + 1];
  float a0 = 0.f, a1 = 0.f, a2 = 0.f, a3 = 0.f;
  float a4 = 0.f, a5 = 0.f, a6 = 0.f, a7 = 0.f, sw = 0.f;
  int p = s;
  for (; p + 8 <= e; p += 8) {
    int j0 = adjj[p],     j1 = adjj[p + 1], j2 = adjj[p + 2], j3 = adjj[p + 3];
    int j4 = adjj[p + 4], j5 = adjj[p + 5], j6 = adjj[p + 6], j7 = adjj[p + 7];
    float w0 = adjw[p],     w1 = adjw[p + 1], w2 = adjw[p + 2], w3 = adjw[p + 3];
    float w4 = adjw[p + 4], w5 = adjw[p + 5], w6 = adjw[p + 6], w7 = adjw[p + 7];
    a0 += w0 * pmatT[(size_t)j0 * KD + k];
    a1 += w1 * pmatT[(size_t)j1 * KD + k];
    a2 += w2 * pmatT[(size_t)j2 * KD + k];
    a3 += w3 * pmatT[(size_t)j3 * KD + k];
    a4 += w4 * pmatT[(size_t)j4 * KD + k];
    a5 += w5 * pmatT[(size_t)j5 * KD + k];
    a6 += w6 * pmatT[(size_t)j6 * KD + k];
    a7 += w7 * pmatT[(size_t)j7 * KD + k];
    sw += w0 + w1 + w2 + w3 + w4 + w5 + w6 + w7;
  }
  for (; p < e; ++p) {
    int jj = adjj[p];
    float w = adjw[p];
    a0 += w * pmatT[(size_t)jj * KD + k];
    sw += w;
  }
  Bout[(size_t)v * KD + k] = sw * pmatT[(size_t)v * KD + k]
                           - ((a0 + a1) + (a2 + a3) + (a4 + a5) + (a6 + a7));
}

// Ladj(512x512) += pmat(512x8192) @ Bm(8192x512): 64x64 tile, 4x4/thread, split-K=8
__global__ __launch_bounds__(256) void gemm_big_k(const float* __restrict__ A,
                                                  const float* __restrict__ B,
                                                  float* __restrict__ C) {
  __shared__ __align__(16) float As[32][68];
  __shared__ __align__(16) float Bs[32][68];
  int tid = threadIdx.x;
  int tx = tid & 15, ty = tid >> 4;
  int n0 = blockIdx.x * 64, m0 = blockIdx.y * 64;
  int kbase = blockIdx.z * (VN / 8);
  float acc[4][4] = {};
  for (int kt = kbase; kt < kbase + VN / 8; kt += 32) {
#pragma unroll
    for (int u = 0; u < 2; ++u) {
      int li = tid * 2 + u;
      int r = li >> 3, c = (li & 7) * 4;
      float4 av = *(const float4*)&A[(size_t)(m0 + r) * VN + kt + c];
      As[c][r] = av.x; As[c + 1][r] = av.y; As[c + 2][r] = av.z; As[c + 3][r] = av.w;
      int rb = li >> 4, cb = (li & 15) * 4;
      *(float4*)&Bs[rb][cb] = *(const float4*)&B[(size_t)(kt + rb) * KD + n0 + cb];
    }
    __syncthreads();
#pragma unroll
    for (int k = 0; k < 32; ++k) {
      float4 av = *(const float4*)&As[k][ty * 4];
      float4 bv = *(const float4*)&Bs[k][tx * 4];
      float am[4] = {av.x, av.y, av.z, av.w};
      float bm[4] = {bv.x, bv.y, bv.z, bv.w};
#pragma unroll
      for (int mi = 0; mi < 4; ++mi)
#pragma unroll
        for (int ni = 0; ni < 4; ++ni) acc[mi][ni] += am[mi] * bm[ni];
    }
    __syncthreads();
  }
#pragma unroll
  for (int mi = 0; mi < 4; ++mi)
#pragma unroll
    for (int ni = 0; ni < 4; ++ni)
      atomicAdd(&C[(m0 + ty * 4 + mi) * KD + n0 + tx * 4 + ni], acc[mi][ni]);
}

// ---------- fp32 K x K GEMM (round-1 proven body) ----------

static __device__ __forceinline__ void g32_body(const float* __restrict__ A,
                                                const float* __restrict__ B,
                                                const float* __restrict__ Dm,
                                                float* __restrict__ C,
                                                float alpha, float beta) {
  __shared__ __align__(16) float As[32][34];
  __shared__ __align__(16) float Bs[32][34];
  int tid = threadIdx.x;
  int tx = tid & 15, ty = tid >> 4;
  int n0 = blockIdx.x * 32, m0 = blockIdx.y * 32;
  float a00 = 0.f, a01 = 0.f, a10 = 0.f, a11 = 0.f;
  for (int kt = 0; kt < KD; kt += 32) {
#pragma unroll
    for (int u = 0; u < 4; ++u) {
      int li = tid * 4 + u;
      int r = li >> 5, c = li & 31;
      As[c][r] = A[(m0 + r) * KD + kt + c];
      Bs[r][c] = B[(kt + r) * KD + n0 + c];
    }
    __syncthreads();
#pragma unroll
    for (int k = 0; k < 32; ++k) {
      float2 av = *(const float2*)&As[k][2 * ty];
      float2 bv = *(const float2*)&Bs[k][2 * tx];
      a00 += av.x * bv.x; a01 += av.x * bv.y;
      a10 += av.y * bv.x; a11 += av.y * bv.y;
    }
    __syncthreads();
  }
  int m = m0 + 2 * ty, n = n0 + 2 * tx;
  float d00 = 0.f, d01 = 0.f, d10 = 0.f, d11 = 0.f;
  if (beta != 0.0f) {
    d00 = Dm[m * KD + n];       d01 = Dm[m * KD + n + 1];
    d10 = Dm[(m + 1) * KD + n]; d11 = Dm[(m + 1) * KD + n + 1];
  }
  C[m * KD + n]           = alpha * a00 + beta * d00;
  C[m * KD + n + 1]       = alpha * a01 + beta * d01;
  C[(m + 1) * KD + n]     = alpha * a10 + beta * d10;
  C[(m + 1) * KD + n + 1] = alpha * a11 + beta * d11;
}

__global__ __launch_bounds__(256) void gemm_kk(const float* __restrict__ A,
                                               const float* __restrict__ B,
                                               const float* __restrict__ Dm,
                                               float* __restrict__ C,
                                               float alpha, float beta) {
  g32_body(A, B, Dm, C, alpha, beta);
}

__global__ __launch_bounds__(256) void gemm_dual32(const float* A0, const float* B0,
                                                   const float* D0, float* C0,
                                                   float alpha0, float beta0,
                                                   const float* A1, const float* B1,
                                                   const float* D1, float* C1,
                                                   float alpha1, float beta1) {
  if (blockIdx.z == 0) g32_body(A0, B0, D0, C0, alpha0, beta0);
  else                 g32_body(A1, B1, D1, C1, alpha1, beta1);
}

// ---------- 2-way-split bf16 MFMA K x K GEMM (round-6 proven, 3 terms) ----------

struct SmemT { ushort a[2][64][40]; ushort b[2][64][40]; };  // 20480 B

static __device__ __forceinline__ void mgemm_s(SmemT* sm,
    const float* Asl, const float* Bsl, const float* Dsl, float* Csl,
    float alpha, float beta, int wsplit) {
  const ushort* Ah = (const ushort*)(Asl + KK);
  const ushort* Al = Ah + KK;
  const ushort* Bh = (const ushort*)(Bsl + KK);
  const ushort* Bl = Bh + KK;
  int tid = threadIdx.x;
  int lane = tid & 63, wave = tid >> 6;
  int wr = wave >> 1, wc = wave & 1;
  int fr = lane & 15, fq = lane >> 4;
  int m0 = blockIdx.y * 64, n0 = blockIdx.x * 64;
  int sr = tid >> 2, skc = (tid & 3) * 8;
  f32x4 acc[2][2] = {};
  for (int kt = 0; kt < KD; kt += 32) {
    *(uint4*)&sm->a[0][sr][skc] = *(const uint4*)&Ah[(size_t)(m0 + sr) * KD + kt + skc];
    *(uint4*)&sm->a[1][sr][skc] = *(const uint4*)&Al[(size_t)(m0 + sr) * KD + kt + skc];
    *(uint4*)&sm->b[0][sr][skc] = *(const uint4*)&Bh[(size_t)(n0 + sr) * KD + kt + skc];
    *(uint4*)&sm->b[1][sr][skc] = *(const uint4*)&Bl[(size_t)(n0 + sr) * KD + kt + skc];
    __syncthreads();
    bf16x8 ah[2], al[2], bh[2], bl[2];
#pragma unroll
    for (int m = 0; m < 2; ++m) {
      ah[m] = *(const bf16x8*)&sm->a[0][wr * 32 + m * 16 + fr][fq * 8];
      al[m] = *(const bf16x8*)&sm->a[1][wr * 32 + m * 16 + fr][fq * 8];
    }
#pragma unroll
    for (int n = 0; n < 2; ++n) {
      bh[n] = *(const bf16x8*)&sm->b[0][wc * 32 + n * 16 + fr][fq * 8];
      bl[n] = *(const bf16x8*)&sm->b[1][wc * 32 + n * 16 + fr][fq * 8];
    }
#pragma unroll
    for (int m = 0; m < 2; ++m)
#pragma unroll
      for (int n = 0; n < 2; ++n) {
        acc[m][n] = __builtin_amdgcn_mfma_f32_16x16x32_bf16(ah[m], bh[n], acc[m][n], 0, 0, 0);
        acc[m][n] = __builtin_amdgcn_mfma_f32_16x16x32_bf16(ah[m], bl[n], acc[m][n], 0, 0, 0);
        acc[m][n] = __builtin_amdgcn_mfma_f32_16x16x32_bf16(al[m], bh[n], acc[m][n], 0, 0, 0);
      }
    __syncthreads();
  }
  ushort* Ch = (ushort*)(Csl + KK);
  ushort* Cl = Ch + KK;
#pragma unroll
  for (int m = 0; m < 2; ++m)
#pragma unroll
    for (int n = 0; n < 2; ++n) {
      int col = n0 + wc * 32 + n * 16 + fr;
#pragma unroll
      for (int j = 0; j < 4; ++j) {
        int row = m0 + wr * 32 + m * 16 + fq * 4 + j;
        float v = alpha * acc[m][n][j];
        if (beta != 0.f) v += beta * Dsl[row * KD + col];
        Csl[row * KD + col] = v;
        if (wsplit) {
          ushort h = f2b(v);
          Ch[row * KD + col] = h;
          Cl[row * KD + col] = f2b(v - b2f(h));
        }
      }
    }
}

// z=0: Pm = Za@Ya ; z=1: Xb = Xa@Ra + Xa ; z=2: Rb = Ra@Ra
__global__ __launch_bounds__(256) void bc3_k(const float* Za, const float* Ya, float* Pm,
                                             const float* Xa, const float* Ra,
                                             float* Xb, float* Rb) {
  __shared__ SmemT sm;
  int z = blockIdx.z;
  if (z == 0)      mgemm_s(&sm, Za, Ya, nullptr, Pm, 1.f, 0.f, 1);
  else if (z == 1) mgemm_s(&sm, Xa, Ra, Xa, Xb, 1.f, 1.f, 1);
  else             mgemm_s(&sm, Ra, Ra, nullptr, Rb, 1.f, 0.f, 1);
}

// inverse-only dual: z=0: Xb = Xa@Ra + Xa ; z=1: Rb = Ra@Ra
__global__ __launch_bounds__(256) void inv2_k(const float* Xa, const float* Ra,
                                              float* Xb, float* Rb) {
  __shared__ SmemT sm;
  if (blockIdx.z == 0) mgemm_s(&sm, Xa, Ra, Xa, Xb, 1.f, 1.f, 1);
  else                 mgemm_s(&sm, Ra, Ra, nullptr, Rb, 1.f, 0.f, 1);
}

__global__ __launch_bounds__(256) void yz2_k(const float* Ya, const float* Za, const float* Pm,
                                             float* Yb, float* Zb) {
  __shared__ SmemT sm;
  if (blockIdx.z == 0) mgemm_s(&sm, Ya, Pm, Ya, Yb, -0.5f, 1.5f, 1);
  else                 mgemm_s(&sm, Pm, Za, Za, Zb, -0.5f, 1.5f, 1);
}

__global__ __launch_bounds__(256) void pm1_k(const float* Za, const float* Ya, float* Pm) {
  __shared__ SmemT sm;
  mgemm_s(&sm, Za, Ya, nullptr, Pm, 1.f, 0.f, 1);
}

// ---------- small utility kernels ----------

__global__ __launch_bounds__(256) void sumsq_k(const float* __restrict__ A, int n,
                                               float* __restrict__ slot) {
  float s = 0.f;
  for (int i = blockIdx.x * 256 + threadIdx.x; i < n; i += gridDim.x * 256) {
    float v = A[i];
    s += v * v;
  }
  __shared__ float p[4];
  s = waveReduceAdd(s);
  if ((threadIdx.x & 63) == 0) p[threadIdx.x >> 6] = s;
  __syncthreads();
  if (threadIdx.x == 0) atomicAdd(slot, p[0] + p[1] + p[2] + p[3]);
}

__global__ __launch_bounds__(512) void trace_k(const float* __restrict__ A,
                                               float* __restrict__ slot) {
  float v = A[(size_t)threadIdx.x * KD + threadIdx.x];
  __shared__ float p[8];
  v = waveReduceAdd(v);
  if ((threadIdx.x & 63) == 0) p[threadIdx.x >> 6] = v;
  __syncthreads();
  if (threadIdx.x == 0) {
    float t = 0.f;
    for (int i = 0; i < 8; ++i) t += p[i];
    slot[0] = t;
  }
}

__global__ __launch_bounds__(512) void trace2_k(const float* __restrict__ A0, float* s0,
                                                const float* __restrict__ A1, float* s1) {
  const float* A = blockIdx.z ? A1 : A0;
  float* slot = blockIdx.z ? s1 : s0;
  float v = A[(size_t)threadIdx.x * KD + threadIdx.x];
  __shared__ float p[8];
  v = waveReduceAdd(v);
  if ((threadIdx.x & 63) == 0) p[threadIdx.x >> 6] = v;
  __syncthreads();
  if (threadIdx.x == 0) {
    float t = 0.f;
    for (int i = 0; i < 8; ++i) t += p[i];
    slot[0] = t;
  }
}

__global__ void derive_k(const float* __restrict__ in, float* __restrict__ o_rsqrt,
                         float* __restrict__ o_qroot) {
  float x = in[0];
  o_rsqrt[0] = 1.0f / sqrtf(x);
  if (o_qroot) o_qroot[0] = powf(x, 0.25f);
}

__global__ __launch_bounds__(256) void setid_const_k(float* __restrict__ C, float val) {
  int idx = blockIdx.x * 256 + threadIdx.x;
  int r = idx >> 9, c = idx & (KD - 1);
  C[idx] = (r == c) ? val : 0.0f;
}

__global__ __launch_bounds__(256) void initinv_split_k(const float* __restrict__ Ladj,
                                                       const float* __restrict__ s,
                                                       float* __restrict__ X,
                                                       float* __restrict__ R) {
  int idx = blockIdx.x * 256 + threadIdx.x;
  int r = idx >> 9, c = idx & (KD - 1);
  float cv = s[0];
  float id = (r == c) ? 1.f : 0.f;
  float xv = id * cv;
  float rv = id - cv * Ladj[idx];
  ushort* Xh = (ushort*)(X + KK); ushort* Xl = Xh + KK;
  ushort* Rh = (ushort*)(R + KK); ushort* Rl = Rh + KK;
  X[idx] = xv; ushort h = f2b(xv); Xh[idx] = h; Xl[idx] = f2b(xv - b2f(h));
  R[idx] = rv; h = f2b(rv);        Rh[idx] = h; Rl[idx] = f2b(rv - b2f(h));
}

__global__ __launch_bounds__(256) void setid_split_k(float* __restrict__ C, float val) {
  int idx = blockIdx.x * 256 + threadIdx.x;
  int r = idx >> 9, c = idx & (KD - 1);
  float v = (r == c) ? val : 0.0f;
  ushort* Chh = (ushort*)(C + KK); ushort* Cll = Chh + KK;
  C[idx] = v; ushort h = f2b(v); Chh[idx] = h; Cll[idx] = f2b(v - b2f(h));
}

__global__ __launch_bounds__(256) void scale_split_k(const float* __restrict__ A,
                                                     const float* __restrict__ s,
                                                     float* __restrict__ C) {
  int idx = blockIdx.x * 256 + threadIdx.x;
  float v = A[idx] * s[0];
  ushort* Chh = (ushort*)(C + KK); ushort* Cll = Chh + KK;
  C[idx] = v; ushort h = f2b(v); Chh[idx] = h; Cll[idx] = f2b(v - b2f(h));
}

__global__ __launch_bounds__(256) void scale32_k(const float* __restrict__ A,
                                                 const float* __restrict__ s,
                                                 float* __restrict__ C) {
  int idx = blockIdx.x * 256 + threadIdx.x;
  C[idx] = A[idx] * s[0];
}

__global__ __launch_bounds__(256) void sym_k(const float* __restrict__ G,
                                             float* __restrict__ Out) {
  int idx = blockIdx.x * 256 + threadIdx.x;
  int r = idx >> 9, c = idx & (KD - 1);
  Out[idx] = 0.5f * (G[idx] + G[c * KD + r]);
}

__global__ void final_k(const float* __restrict__ scal, float* __restrict__ out) {
  out[0] = scal[S_TR_X] + scal[S_TR_S0] - 2.0f * scal[S_QRT_CG] * scal[S_TR_YG];
}

// ---------- host ----------

extern "C" void kernel_launch(void* const* d_in, const int* in_sizes, int n_in,
                              void* d_out, int out_size, void* d_ws, size_t ws_size,
                              hipStream_t stream) {
  (void)in_sizes; (void)n_in; (void)out_size; (void)ws_size;
  const float* x    = (const float*)d_in[0];  // V x D
  const float* S0   = (const float*)d_in[1];  // K x K
  const int*   ei   = (const int*)d_in[2];    // 2 x E
  const float* pmat = (const float*)d_in[3];  // K x V
  float* out = (float*)d_out;
  char* ws = (char*)d_ws;
  const size_t MB = 1u << 20;
  const size_t SLOT = 2 * MB;  // f32 + h + l

  unsigned* bitmap = (unsigned*)ws;           // [0,8M), dead after count_k
  float* pmatT = (float*)(ws + 8 * MB);       // [8,24M), dead after buildB_k
  float* Bm    = (float*)(ws + 24 * MB);      // [24,40M), dead after gemm_big_k
  float* Ladj  = (float*)(ws + 40 * MB);      // over ea (dead after fill_k); alive to inv polish
  float* Gs    = (float*)(ws + 41 * MB);      // over eb (dead after fill_k); stage D
  int*   ea     = (int*)(ws + 40 * MB);       // dead after fill_k
  int*   eb     = (int*)(ws + 41 * MB);       // dead after fill_k
  float* ew     = (float*)(ws + 42 * MB);     // dead after fill_k
  int*   adjj   = (int*)(ws + 43 * MB);       // 2 MB, dead after buildB_k
  float* adjw   = (float*)(ws + 45 * MB);     // 2 MB, dead after buildB_k
  int*   cnt    = (int*)(ws + 47 * MB);
  int*   rowptr = (int*)(ws + 47 * MB + 64 * 1024);
  int*   cursor = (int*)(ws + 47 * MB + 128 * 1024);
  float* scal   = (float*)(ws + 47 * MB + 256 * 1024);
  float* SL[11];
  for (int i = 0; i < 11; ++i) SL[i] = (float*)(ws + (size_t)i * SLOT);
  float *Xa = SL[0], *Ra = SL[1], *Ya = SL[2], *Za = SL[3];
  float *Xb = SL[4], *Rb = SL[5], *Yb = SL[6], *Zb = SL[7];
  float *Pm = SL[8], *S0h = SL[9], *TMP = SL[10];

  hipMemsetAsync(bitmap, 0, (size_t)VN * VN / 8, stream);
  hipMemsetAsync(cnt, 0, (size_t)VN * 4, stream);
  hipMemsetAsync(scal, 0, 64 * 4, stream);

  // stage A: graph construction -> L_adj (fp32, PSD-safe)
  transpose_k<<<dim3(VN / 32, KD / 32), 256, 0, stream>>>(pmat, pmatT);
  count_k<<<EN / 16, 256, 0, stream>>>(x, ei, ea, eb, ew, cnt, bitmap);
  scan_k<<<1, 1024, 0, stream>>>(cnt, rowptr, cursor);
  fill_k<<<EN / 256, 256, 0, stream>>>(ea, eb, ew, cursor, adjj, adjw);
  buildB_k<<<VN, 512, 0, stream>>>(pmatT, rowptr, adjj, adjw, Bm);
  setid_const_k<<<KK / 256, 256, 0, stream>>>(Ladj, 1e-5f);
  gemm_big_k<<<dim3(8, 8, 8), 256, 0, stream>>>(pmat, Bm, Ladj);

  // stage B prep: residual-form inverse NS
  sumsq_k<<<256, 256, 0, stream>>>(Ladj, KK, &scal[S_SS_LADJ]);
  derive_k<<<1, 1, 0, stream>>>(&scal[S_SS_LADJ], &scal[S_INV_C1], nullptr);
  initinv_split_k<<<KK / 256, 256, 0, stream>>>(Ladj, &scal[S_INV_C1], Xa, Ra);

  // stage C prep: coupled sqrt NS on S0/||S0||_F
  sumsq_k<<<256, 256, 0, stream>>>(S0, KK, &scal[S_SS_S0]);
  derive_k<<<1, 1, 0, stream>>>(&scal[S_SS_S0], &scal[S_INV_C0], &scal[S_QRT_C0]);
  scale_split_k<<<KK / 256, 256, 0, stream>>>(S0, &scal[S_INV_C0], Ya);
  setid_split_k<<<KK / 256, 256, 0, stream>>>(Za, 1.0f);

  // MFMA: 12 packed rounds (inv + sqrtS0), then 3 inv-only rounds (inv total 15)
  // sqrtS0 at 12 rounds + 1 fp32 polish = 2^13 contraction; a_min(S0) = 0.1/||S0||_F
  // ~ 2.6e-3 -> e^{-21}: fully converged.
  for (int r = 0; r < 12; ++r) {
    bc3_k<<<dim3(8, 8, 3), 256, 0, stream>>>(Za, Ya, Pm, Xa, Ra, Xb, Rb);
    yz2_k<<<dim3(8, 8, 2), 256, 0, stream>>>(Ya, Za, Pm, Yb, Zb);
    float* t = Xa; Xa = Xb; Xb = t;
    t = Ra; Ra = Rb; Rb = t;
    t = Ya; Ya = Yb; Yb = t;
    t = Za; Za = Zb; Zb = t;
  }
  for (int r = 0; r < 3; ++r) {
    inv2_k<<<dim3(8, 8, 2), 256, 0, stream>>>(Xa, Ra, Xb, Rb);
    float* t = Xa; Xa = Xb; Xb = t;
    t = Ra; Ra = Rb; Rb = t;
  }

  // packed polish L1: {U32 = Ladj@Xa} || {Pm = Za@Ya}   (independent chains)
  float* U32  = Xb;
  float* Xfin = Rb;
  gemm_dual32<<<dim3(16, 16, 2), 256, 0, stream>>>(Ladj, Xa, nullptr, U32, 1.0f, 0.0f,
                                                   Za, Ya, nullptr, Pm, 1.0f, 0.0f);
  // packed polish L2: {Xfin = 2Xa - Xa@U32} || {Yb = 1.5Ya - 0.5 Ya@Pm}
  gemm_dual32<<<dim3(16, 16, 2), 256, 0, stream>>>(Xa, U32, Xa, Xfin, -1.0f, 2.0f,
                                                   Ya, Pm, Ya, Yb, -0.5f, 1.5f);
  trace2_k<<<dim3(1, 1, 2), 512, 0, stream>>>(Xfin, &scal[S_TR_X], S0, &scal[S_TR_S0]);
  scale32_k<<<KK / 256, 256, 0, stream>>>(Yb, &scal[S_QRT_C0], S0h);

  // stage D: G = S0h @ S1 @ S0h in fp32
  gemm_kk<<<dim3(16, 16), 256, 0, stream>>>(S0h, Xfin, nullptr, TMP, 1.0f, 0.0f);
  gemm_kk<<<dim3(16, 16), 256, 0, stream>>>(TMP, S0h, nullptr, Gs, 1.0f, 0.0f);
  sym_k<<<KK / 256, 256, 0, stream>>>(Gs, TMP);   // TMP = sym(G), fp32
  sumsq_k<<<256, 256, 0, stream>>>(TMP, KK, &scal[S_SS_G]);
  derive_k<<<1, 1, 0, stream>>>(&scal[S_SS_G], &scal[S_INV_CG], &scal[S_QRT_CG]);
  scale_split_k<<<KK / 256, 256, 0, stream>>>(TMP, &scal[S_INV_CG], Ya);
  setid_split_k<<<KK / 256, 256, 0, stream>>>(Za, 1.0f);
  // MFMA sqrt(G): 20 rounds (soft-mode tail needs every doubling — do not trim)
  for (int r = 0; r < 20; ++r) {
    pm1_k<<<dim3(8, 8, 1), 256, 0, stream>>>(Za, Ya, Pm);
    yz2_k<<<dim3(8, 8, 2), 256, 0, stream>>>(Ya, Za, Pm, Yb, Zb);
    float* t = Ya; Ya = Yb; Yb = t;
    t = Za; Za = Zb; Zb = t;
  }
  // sqrt(G) polish: two fp32 NS iterations
  gemm_kk<<<dim3(16, 16), 256, 0, stream>>>(Za, Ya, nullptr, Pm, 1.0f, 0.0f);
  gemm_dual32<<<dim3(16, 16, 2), 256, 0, stream>>>(Ya, Pm, Ya, Yb, -0.5f, 1.5f,
                                                   Pm, Za, Za, Zb, -0.5f, 1.5f);
  gemm_kk<<<dim3(16, 16), 256, 0, stream>>>(Zb, Yb, nullptr, Pm, 1.0f, 0.0f);
  gemm_kk<<<dim3(16, 16), 256, 0, stream>>>(Yb, Pm, Yb, S0h, -0.5f, 1.5f);  // S0h = Y_final
  trace_k<<<1, 512, 0, stream>>>(S0h, &scal[S_TR_YG]);

  final_k<<<1, 1, 0, stream>>>(scal, out);
}

// Round 15
// 1382.465 us; speedup vs baseline: 5.1732x; 1.0285x over previous
//
#include <hip/hip_runtime.h>
#include <math.h>

#define VN 8192
#define DN 128
#define EN 262144
#define KD 512
#define KK (KD*KD)

// scalar slots
#define S_SS_LADJ 0
#define S_INV_C1  1
#define S_SS_S0   2
#define S_INV_C0  3
#define S_QRT_C0  4
#define S_SS_G    5
#define S_INV_CG  6
#define S_QRT_CG  7
#define S_TR_X    8
#define S_TR_S0   9
#define S_TR_YG   10

typedef __attribute__((ext_vector_type(8))) __bf16 bf16x8;
typedef __attribute__((ext_vector_type(4))) float f32x4;

static __device__ __forceinline__ float waveReduceAdd(float v) {
#pragma unroll
  for (int o = 32; o; o >>= 1) v += __shfl_xor(v, o);
  return v;
}

static __device__ __forceinline__ ushort f2b(float f) {
  unsigned x = __float_as_uint(f);
  unsigned r = (x + 0x7fffu + ((x >> 16) & 1u)) >> 16;
  return (ushort)r;
}
static __device__ __forceinline__ float b2f(ushort u) {
  return __uint_as_float((unsigned)u << 16);
}

// ---------- stage A: graph -> L_adj (fp32, proven path) ----------

__global__ __launch_bounds__(256) void transpose_k(const float* __restrict__ in,
                                                   float* __restrict__ out) {
  __shared__ float s[32][33];
  int tx = threadIdx.x & 31, ty = threadIdx.x >> 5;
  int v0 = blockIdx.x * 32, k0 = blockIdx.y * 32;
  for (int r = ty; r < 32; r += 8) s[r][tx] = in[(size_t)(k0 + r) * VN + v0 + tx];
  __syncthreads();
  for (int r = ty; r < 32; r += 8) out[(size_t)(v0 + r) * KD + k0 + tx] = s[tx][r];
}

// 4 edges per wave (16-lane groups), float4 distance loads
__global__ __launch_bounds__(256) void count_k(const float* __restrict__ x,
                                               const int* __restrict__ ei,
                                               int* __restrict__ ea, int* __restrict__ eb,
                                               float* __restrict__ ew,
                                               int* __restrict__ cnt,
                                               unsigned int* __restrict__ bitmap) {
  int e = (int)(((unsigned)blockIdx.x * 256u + threadIdx.x) >> 4);
  int lane = threadIdx.x & 63;
  int sl = lane & 15;
  if (e >= EN) return;
  int i = ei[e], j = ei[EN + e];
  int a = i < j ? i : j;
  int b = i < j ? j : i;
  int ok = 0;
  if (sl == 0) {
    if (i != j) {
      unsigned key = (unsigned)a * (unsigned)VN + (unsigned)b;
      unsigned m = 1u << (key & 31u);
      unsigned old = atomicOr(bitmap + (key >> 5), m);
      ok = (old & m) ? 0 : 1;
    }
  }
  ok = __shfl(ok, lane & 48);  // broadcast from group leader
  if (!ok) { if (sl == 0) ea[e] = -1; return; }
  const float4* xa = (const float4*)&x[(size_t)a * DN + sl * 8];
  const float4* xb = (const float4*)&x[(size_t)b * DN + sl * 8];
  float4 a0 = xa[0], a1 = xa[1], b0 = xb[0], b1 = xb[1];
  float d0 = a0.x - b0.x, d1 = a0.y - b0.y, d2 = a0.z - b0.z, d3 = a0.w - b0.w;
  float d4 = a1.x - b1.x, d5 = a1.y - b1.y, d6 = a1.z - b1.z, d7 = a1.w - b1.w;
  float s = d0*d0 + d1*d1 + d2*d2 + d3*d3 + d4*d4 + d5*d5 + d6*d6 + d7*d7;
#pragma unroll
  for (int o = 8; o; o >>= 1) s += __shfl_xor(s, o);
  if (sl == 0) {
    ea[e] = a; eb[e] = b; ew[e] = expf(-s);
    atomicAdd(cnt + a, 1);
    atomicAdd(cnt + b, 1);
  }
}

__global__ __launch_bounds__(1024) void scan_k(const int* __restrict__ cnt,
                                               int* __restrict__ rowptr,
                                               int* __restrict__ cursor) {
  __shared__ int sd[1024];
  __shared__ int carry;
  int tid = threadIdx.x;
  if (tid == 0) { carry = 0; rowptr[0] = 0; }
  __syncthreads();
  for (int c = 0; c < VN / 1024; ++c) {
    int v = c * 1024 + tid;
    int xv = cnt[v];
    sd[tid] = xv;
    __syncthreads();
    for (int off = 1; off < 1024; off <<= 1) {
      int t = (tid >= off) ? sd[tid - off] : 0;
      __syncthreads();
      sd[tid] += t;
      __syncthreads();
    }
    int incl = sd[tid];
    int base = carry;
    rowptr[v + 1] = base + incl;
    cursor[v] = base + incl - xv;
    __syncthreads();
    if (tid == 1023) carry = base + incl;
    __syncthreads();
  }
}

__global__ __launch_bounds__(256) void fill_k(const int* __restrict__ ea, const int* __restrict__ eb,
                                              const float* __restrict__ ew,
                                              int* __restrict__ cursor,
                                              int* __restrict__ adjj, float* __restrict__ adjw) {
  int e = blockIdx.x * 256 + threadIdx.x;
  if (e >= EN) return;
  int a = ea[e];
  if (a < 0) return;
  int b = eb[e];
  float w = ew[e];
  int p = atomicAdd(cursor + a, 1); adjj[p] = b; adjw[p] = w;
  int q = atomicAdd(cursor + b, 1); adjj[q] = a; adjw[q] = w;
}

// one vertex per block; gather loop unrolled x8
__global__ __launch_bounds__(512) void buildB_k(const float* __restrict__ pmatT,
                                                const int* __restrict__ rowptr,
                                                const int* __restrict__ adjj,
                                                const float* __restrict__ adjw,
                                                float* __restrict__ Bout) {
  int v = blockIdx.x;
  int k = threadIdx.x;
  int s = rowptr[v], e = rowptr[v + 1];
  float a0 = 0.f, a1 = 0.f, a2 = 0.f, a3 = 0.f;
  float a4 = 0.f, a5 = 0.f, a6 = 0.f, a7 = 0.f, sw = 0.f;
  int p = s;
  for (; p + 8 <= e; p += 8) {
    int j0 = adjj[p],     j1 = adjj[p + 1], j2 = adjj[p + 2], j3 = adjj[p + 3];
    int j4 = adjj[p + 4], j5 = adjj[p + 5], j6 = adjj[p + 6], j7 = adjj[p + 7];
    float w0 = adjw[p],     w1 = adjw[p + 1], w2 = adjw[p + 2], w3 = adjw[p + 3];
    float w4 = adjw[p + 4], w5 = adjw[p + 5], w6 = adjw[p + 6], w7 = adjw[p + 7];
    a0 += w0 * pmatT[(size_t)j0 * KD + k];
    a1 += w1 * pmatT[(size_t)j1 * KD + k];
    a2 += w2 * pmatT[(size_t)j2 * KD + k];
    a3 += w3 * pmatT[(size_t)j3 * KD + k];
    a4 += w4 * pmatT[(size_t)j4 * KD + k];
    a5 += w5 * pmatT[(size_t)j5 * KD + k];
    a6 += w6 * pmatT[(size_t)j6 * KD + k];
    a7 += w7 * pmatT[(size_t)j7 * KD + k];
    sw += w0 + w1 + w2 + w3 + w4 + w5 + w6 + w7;
  }
  for (; p < e; ++p) {
    int jj = adjj[p];
    float w = adjw[p];
    a0 += w * pmatT[(size_t)jj * KD + k];
    sw += w;
  }
  Bout[(size_t)v * KD + k] = sw * pmatT[(size_t)v * KD + k]
                           - ((a0 + a1) + (a2 + a3) + (a4 + a5) + (a6 + a7));
}

// Ladj(512x512) += pmat(512x8192) @ Bm(8192x512): 64x64 tile, 4x4/thread, split-K=8
__global__ __launch_bounds__(256) void gemm_big_k(const float* __restrict__ A,
                                                  const float* __restrict__ B,
                                                  float* __restrict__ C) {
  __shared__ __align__(16) float As[32][68];
  __shared__ __align__(16) float Bs[32][68];
  int tid = threadIdx.x;
  int tx = tid & 15, ty = tid >> 4;
  int n0 = blockIdx.x * 64, m0 = blockIdx.y * 64;
  int kbase = blockIdx.z * (VN / 8);
  float acc[4][4] = {};
  for (int kt = kbase; kt < kbase + VN / 8; kt += 32) {
#pragma unroll
    for (int u = 0; u < 2; ++u) {
      int li = tid * 2 + u;
      int r = li >> 3, c = (li & 7) * 4;
      float4 av = *(const float4*)&A[(size_t)(m0 + r) * VN + kt + c];
      As[c][r] = av.x; As[c + 1][r] = av.y; As[c + 2][r] = av.z; As[c + 3][r] = av.w;
      int rb = li >> 4, cb = (li & 15) * 4;
      *(float4*)&Bs[rb][cb] = *(const float4*)&B[(size_t)(kt + rb) * KD + n0 + cb];
    }
    __syncthreads();
#pragma unroll
    for (int k = 0; k < 32; ++k) {
      float4 av = *(const float4*)&As[k][ty * 4];
      float4 bv = *(const float4*)&Bs[k][tx * 4];
      float am[4] = {av.x, av.y, av.z, av.w};
      float bm[4] = {bv.x, bv.y, bv.z, bv.w};
#pragma unroll
      for (int mi = 0; mi < 4; ++mi)
#pragma unroll
        for (int ni = 0; ni < 4; ++ni) acc[mi][ni] += am[mi] * bm[ni];
    }
    __syncthreads();
  }
#pragma unroll
  for (int mi = 0; mi < 4; ++mi)
#pragma unroll
    for (int ni = 0; ni < 4; ++ni)
      atomicAdd(&C[(m0 + ty * 4 + mi) * KD + n0 + tx * 4 + ni], acc[mi][ni]);
}

// ---------- fp32 K x K GEMM (round-1 proven body) ----------

static __device__ __forceinline__ void g32_body(const float* __restrict__ A,
                                                const float* __restrict__ B,
                                                const float* __restrict__ Dm,
                                                float* __restrict__ C,
                                                float alpha, float beta) {
  __shared__ __align__(16) float As[32][34];
  __shared__ __align__(16) float Bs[32][34];
  int tid = threadIdx.x;
  int tx = tid & 15, ty = tid >> 4;
  int n0 = blockIdx.x * 32, m0 = blockIdx.y * 32;
  float a00 = 0.f, a01 = 0.f, a10 = 0.f, a11 = 0.f;
  for (int kt = 0; kt < KD; kt += 32) {
#pragma unroll
    for (int u = 0; u < 4; ++u) {
      int li = tid * 4 + u;
      int r = li >> 5, c = li & 31;
      As[c][r] = A[(m0 + r) * KD + kt + c];
      Bs[r][c] = B[(kt + r) * KD + n0 + c];
    }
    __syncthreads();
#pragma unroll
    for (int k = 0; k < 32; ++k) {
      float2 av = *(const float2*)&As[k][2 * ty];
      float2 bv = *(const float2*)&Bs[k][2 * tx];
      a00 += av.x * bv.x; a01 += av.x * bv.y;
      a10 += av.y * bv.x; a11 += av.y * bv.y;
    }
    __syncthreads();
  }
  int m = m0 + 2 * ty, n = n0 + 2 * tx;
  float d00 = 0.f, d01 = 0.f, d10 = 0.f, d11 = 0.f;
  if (beta != 0.0f) {
    d00 = Dm[m * KD + n];       d01 = Dm[m * KD + n + 1];
    d10 = Dm[(m + 1) * KD + n]; d11 = Dm[(m + 1) * KD + n + 1];
  }
  C[m * KD + n]           = alpha * a00 + beta * d00;
  C[m * KD + n + 1]       = alpha * a01 + beta * d01;
  C[(m + 1) * KD + n]     = alpha * a10 + beta * d10;
  C[(m + 1) * KD + n + 1] = alpha * a11 + beta * d11;
}

__global__ __launch_bounds__(256) void gemm_kk(const float* __restrict__ A,
                                               const float* __restrict__ B,
                                               const float* __restrict__ Dm,
                                               float* __restrict__ C,
                                               float alpha, float beta) {
  g32_body(A, B, Dm, C, alpha, beta);
}

__global__ __launch_bounds__(256) void gemm_dual32(const float* A0, const float* B0,
                                                   const float* D0, float* C0,
                                                   float alpha0, float beta0,
                                                   const float* A1, const float* B1,
                                                   const float* D1, float* C1,
                                                   float alpha1, float beta1) {
  if (blockIdx.z == 0) g32_body(A0, B0, D0, C0, alpha0, beta0);
  else                 g32_body(A1, B1, D1, C1, alpha1, beta1);
}

// ---------- 2-way-split bf16 MFMA K x K GEMM, double-buffered staging ----------
// Slot (2 MB): [0,1M) f32 master, h [1M,1.5M), l [1.5M,2M).
// C = alpha*(A@B) + beta*D via Ah*Bh + Ah*Bl + Al*Bh (fp32 acc, same order as r6).
// Staging: issue kt+1 global loads into regs before kt's MFMAs; one barrier/iter.

struct SmemT { ushort a[2][2][64][40]; ushort b[2][2][64][40]; };  // 40960 B

static __device__ __forceinline__ void mgemm_s(SmemT* sm,
    const float* Asl, const float* Bsl, const float* Dsl, float* Csl,
    float alpha, float beta, int wsplit) {
  const ushort* Ah = (const ushort*)(Asl + KK);
  const ushort* Al = Ah + KK;
  const ushort* Bh = (const ushort*)(Bsl + KK);
  const ushort* Bl = Bh + KK;
  int tid = threadIdx.x;
  int lane = tid & 63, wave = tid >> 6;
  int wr = wave >> 1, wc = wave & 1;
  int fr = lane & 15, fq = lane >> 4;
  int m0 = blockIdx.y * 64, n0 = blockIdx.x * 64;
  int sr = tid >> 2, skc = (tid & 3) * 8;
  const size_t aoff = (size_t)(m0 + sr) * KD + skc;
  const size_t boff = (size_t)(n0 + sr) * KD + skc;
  f32x4 acc[2][2] = {};
  // preload kt=0 into buf 0
  uint4 va0 = *(const uint4*)&Ah[aoff];
  uint4 va1 = *(const uint4*)&Al[aoff];
  uint4 vb0 = *(const uint4*)&Bh[boff];
  uint4 vb1 = *(const uint4*)&Bl[boff];
  *(uint4*)&sm->a[0][0][sr][skc] = va0;
  *(uint4*)&sm->a[0][1][sr][skc] = va1;
  *(uint4*)&sm->b[0][0][sr][skc] = vb0;
  *(uint4*)&sm->b[0][1][sr][skc] = vb1;
  __syncthreads();
  for (int it = 0; it < 16; ++it) {
    int cur = it & 1, nxt = cur ^ 1;
    if (it < 15) {
      size_t ktn = (size_t)(it + 1) * 32;
      va0 = *(const uint4*)&Ah[aoff + ktn];
      va1 = *(const uint4*)&Al[aoff + ktn];
      vb0 = *(const uint4*)&Bh[boff + ktn];
      vb1 = *(const uint4*)&Bl[boff + ktn];
    }
    bf16x8 ah[2], al[2], bh[2], bl[2];
#pragma unroll
    for (int m = 0; m < 2; ++m) {
      ah[m] = *(const bf16x8*)&sm->a[cur][0][wr * 32 + m * 16 + fr][fq * 8];
      al[m] = *(const bf16x8*)&sm->a[cur][1][wr * 32 + m * 16 + fr][fq * 8];
    }
#pragma unroll
    for (int n = 0; n < 2; ++n) {
      bh[n] = *(const bf16x8*)&sm->b[cur][0][wc * 32 + n * 16 + fr][fq * 8];
      bl[n] = *(const bf16x8*)&sm->b[cur][1][wc * 32 + n * 16 + fr][fq * 8];
    }
#pragma unroll
    for (int m = 0; m < 2; ++m)
#pragma unroll
      for (int n = 0; n < 2; ++n) {
        acc[m][n] = __builtin_amdgcn_mfma_f32_16x16x32_bf16(ah[m], bh[n], acc[m][n], 0, 0, 0);
        acc[m][n] = __builtin_amdgcn_mfma_f32_16x16x32_bf16(ah[m], bl[n], acc[m][n], 0, 0, 0);
        acc[m][n] = __builtin_amdgcn_mfma_f32_16x16x32_bf16(al[m], bh[n], acc[m][n], 0, 0, 0);
      }
    if (it < 15) {
      *(uint4*)&sm->a[nxt][0][sr][skc] = va0;
      *(uint4*)&sm->a[nxt][1][sr][skc] = va1;
      *(uint4*)&sm->b[nxt][0][sr][skc] = vb0;
      *(uint4*)&sm->b[nxt][1][sr][skc] = vb1;
    }
    __syncthreads();
  }
  ushort* Ch = (ushort*)(Csl + KK);
  ushort* Cl = Ch + KK;
#pragma unroll
  for (int m = 0; m < 2; ++m)
#pragma unroll
    for (int n = 0; n < 2; ++n) {
      int col = n0 + wc * 32 + n * 16 + fr;
#pragma unroll
      for (int j = 0; j < 4; ++j) {
        int row = m0 + wr * 32 + m * 16 + fq * 4 + j;
        float v = alpha * acc[m][n][j];
        if (beta != 0.f) v += beta * Dsl[row * KD + col];
        Csl[row * KD + col] = v;
        if (wsplit) {
          ushort h = f2b(v);
          Ch[row * KD + col] = h;
          Cl[row * KD + col] = f2b(v - b2f(h));
        }
      }
    }
}

// z=0: Pm = Za@Ya ; z=1: Xb = Xa@Ra + Xa ; z=2: Rb = Ra@Ra
__global__ __launch_bounds__(256) void bc3_k(const float* Za, const float* Ya, float* Pm,
                                             const float* Xa, const float* Ra,
                                             float* Xb, float* Rb) {
  __shared__ SmemT sm;
  int z = blockIdx.z;
  if (z == 0)      mgemm_s(&sm, Za, Ya, nullptr, Pm, 1.f, 0.f, 1);
  else if (z == 1) mgemm_s(&sm, Xa, Ra, Xa, Xb, 1.f, 1.f, 1);
  else             mgemm_s(&sm, Ra, Ra, nullptr, Rb, 1.f, 0.f, 1);
}

// inverse-only dual: z=0: Xb = Xa@Ra + Xa ; z=1: Rb = Ra@Ra
__global__ __launch_bounds__(256) void inv2_k(const float* Xa, const float* Ra,
                                              float* Xb, float* Rb) {
  __shared__ SmemT sm;
  if (blockIdx.z == 0) mgemm_s(&sm, Xa, Ra, Xa, Xb, 1.f, 1.f, 1);
  else                 mgemm_s(&sm, Ra, Ra, nullptr, Rb, 1.f, 0.f, 1);
}

__global__ __launch_bounds__(256) void yz2_k(const float* Ya, const float* Za, const float* Pm,
                                             float* Yb, float* Zb) {
  __shared__ SmemT sm;
  if (blockIdx.z == 0) mgemm_s(&sm, Ya, Pm, Ya, Yb, -0.5f, 1.5f, 1);
  else                 mgemm_s(&sm, Pm, Za, Za, Zb, -0.5f, 1.5f, 1);
}

__global__ __launch_bounds__(256) void pm1_k(const float* Za, const float* Ya, float* Pm) {
  __shared__ SmemT sm;
  mgemm_s(&sm, Za, Ya, nullptr, Pm, 1.f, 0.f, 1);
}

// ---------- small utility kernels ----------

__global__ __launch_bounds__(256) void sumsq_k(const float* __restrict__ A, int n,
                                               float* __restrict__ slot) {
  float s = 0.f;
  for (int i = blockIdx.x * 256 + threadIdx.x; i < n; i += gridDim.x * 256) {
    float v = A[i];
    s += v * v;
  }
  __shared__ float p[4];
  s = waveReduceAdd(s);
  if ((threadIdx.x & 63) == 0) p[threadIdx.x >> 6] = s;
  __syncthreads();
  if (threadIdx.x == 0) atomicAdd(slot, p[0] + p[1] + p[2] + p[3]);
}

// two independent sumsq in one launch (z picks)
__global__ __launch_bounds__(256) void sumsq2_k(const float* __restrict__ A0, float* s0,
                                                const float* __restrict__ A1, float* s1) {
  const float* A = blockIdx.z ? A1 : A0;
  float* slot = blockIdx.z ? s1 : s0;
  float s = 0.f;
  for (int i = blockIdx.x * 256 + threadIdx.x; i < KK; i += gridDim.x * 256) {
    float v = A[i];
    s += v * v;
  }
  __shared__ float p[4];
  s = waveReduceAdd(s);
  if ((threadIdx.x & 63) == 0) p[threadIdx.x >> 6] = s;
  __syncthreads();
  if (threadIdx.x == 0) atomicAdd(slot, p[0] + p[1] + p[2] + p[3]);
}

__global__ __launch_bounds__(512) void trace_k(const float* __restrict__ A,
                                               float* __restrict__ slot) {
  float v = A[(size_t)threadIdx.x * KD + threadIdx.x];
  __shared__ float p[8];
  v = waveReduceAdd(v);
  if ((threadIdx.x & 63) == 0) p[threadIdx.x >> 6] = v;
  __syncthreads();
  if (threadIdx.x == 0) {
    float t = 0.f;
    for (int i = 0; i < 8; ++i) t += p[i];
    slot[0] = t;
  }
}

__global__ __launch_bounds__(512) void trace2_k(const float* __restrict__ A0, float* s0,
                                                const float* __restrict__ A1, float* s1) {
  const float* A = blockIdx.z ? A1 : A0;
  float* slot = blockIdx.z ? s1 : s0;
  float v = A[(size_t)threadIdx.x * KD + threadIdx.x];
  __shared__ float p[8];
  v = waveReduceAdd(v);
  if ((threadIdx.x & 63) == 0) p[threadIdx.x >> 6] = v;
  __syncthreads();
  if (threadIdx.x == 0) {
    float t = 0.f;
    for (int i = 0; i < 8; ++i) t += p[i];
    slot[0] = t;
  }
}

__global__ void derive_k(const float* __restrict__ in, float* __restrict__ o_rsqrt,
                         float* __restrict__ o_qroot) {
  float x = in[0];
  o_rsqrt[0] = 1.0f / sqrtf(x);
  if (o_qroot) o_qroot[0] = powf(x, 0.25f);
}

// derive for Ladj (rsqrt) and S0 (rsqrt + qroot) in one tiny launch
__global__ void derive2_k(float* __restrict__ scal) {
  if (threadIdx.x == 0) {
    scal[S_INV_C1] = 1.0f / sqrtf(scal[S_SS_LADJ]);
  } else if (threadIdx.x == 1) {
    float x = scal[S_SS_S0];
    scal[S_INV_C0] = 1.0f / sqrtf(x);
    scal[S_QRT_C0] = powf(x, 0.25f);
  }
}

__global__ __launch_bounds__(256) void setid_const_k(float* __restrict__ C, float val) {
  int idx = blockIdx.x * 256 + threadIdx.x;
  int r = idx >> 9, c = idx & (KD - 1);
  C[idx] = (r == c) ? val : 0.0f;
}

__global__ __launch_bounds__(256) void initinv_split_k(const float* __restrict__ Ladj,
                                                       const float* __restrict__ s,
                                                       float* __restrict__ X,
                                                       float* __restrict__ R) {
  int idx = blockIdx.x * 256 + threadIdx.x;
  int r = idx >> 9, c = idx & (KD - 1);
  float cv = s[0];
  float id = (r == c) ? 1.f : 0.f;
  float xv = id * cv;
  float rv = id - cv * Ladj[idx];
  ushort* Xh = (ushort*)(X + KK); ushort* Xl = Xh + KK;
  ushort* Rh = (ushort*)(R + KK); ushort* Rl = Rh + KK;
  X[idx] = xv; ushort h = f2b(xv); Xh[idx] = h; Xl[idx] = f2b(xv - b2f(h));
  R[idx] = rv; h = f2b(rv);        Rh[idx] = h; Rl[idx] = f2b(rv - b2f(h));
}

// z=0: Cs = scale-split(A * s[0]) ; z=1: Ci = setid-split(1.0)
__global__ __launch_bounds__(256) void prep2_k(const float* __restrict__ A,
                                               const float* __restrict__ s,
                                               float* __restrict__ Cs,
                                               float* __restrict__ Ci) {
  int idx = blockIdx.x * 256 + threadIdx.x;
  if (blockIdx.z == 0) {
    float v = A[idx] * s[0];
    ushort* Chh = (ushort*)(Cs + KK); ushort* Cll = Chh + KK;
    Cs[idx] = v; ushort h = f2b(v); Chh[idx] = h; Cll[idx] = f2b(v - b2f(h));
  } else {
    int r = idx >> 9, c = idx & (KD - 1);
    float v = (r == c) ? 1.0f : 0.0f;
    ushort* Chh = (ushort*)(Ci + KK); ushort* Cll = Chh + KK;
    Ci[idx] = v; ushort h = f2b(v); Chh[idx] = h; Cll[idx] = f2b(v - b2f(h));
  }
}

__global__ __launch_bounds__(256) void scale32_k(const float* __restrict__ A,
                                                 const float* __restrict__ s,
                                                 float* __restrict__ C) {
  int idx = blockIdx.x * 256 + threadIdx.x;
  C[idx] = A[idx] * s[0];
}

// fused: Out = sym(G); slot += ||Out||_F^2
__global__ __launch_bounds__(256) void symss_k(const float* __restrict__ G,
                                               float* __restrict__ Out,
                                               float* __restrict__ slot) {
  int idx = blockIdx.x * 256 + threadIdx.x;
  int r = idx >> 9, c = idx & (KD - 1);
  float v = 0.5f * (G[idx] + G[c * KD + r]);
  Out[idx] = v;
  float s = v * v;
  __shared__ float p[4];
  s = waveReduceAdd(s);
  if ((threadIdx.x & 63) == 0) p[threadIdx.x >> 6] = s;
  __syncthreads();
  if (threadIdx.x == 0) atomicAdd(slot, p[0] + p[1] + p[2] + p[3]);
}

__global__ void final_k(const float* __restrict__ scal, float* __restrict__ out) {
  out[0] = scal[S_TR_X] + scal[S_TR_S0] - 2.0f * scal[S_QRT_CG] * scal[S_TR_YG];
}

// ---------- host ----------

extern "C" void kernel_launch(void* const* d_in, const int* in_sizes, int n_in,
                              void* d_out, int out_size, void* d_ws, size_t ws_size,
                              hipStream_t stream) {
  (void)in_sizes; (void)n_in; (void)out_size; (void)ws_size;
  const float* x    = (const float*)d_in[0];  // V x D
  const float* S0   = (const float*)d_in[1];  // K x K
  const int*   ei   = (const int*)d_in[2];    // 2 x E
  const float* pmat = (const float*)d_in[3];  // K x V
  float* out = (float*)d_out;
  char* ws = (char*)d_ws;
  const size_t MB = 1u << 20;
  const size_t SLOT = 2 * MB;  // f32 + h + l

  unsigned* bitmap = (unsigned*)ws;           // [0,8M), dead after count_k
  float* pmatT = (float*)(ws + 8 * MB);       // [8,24M), dead after buildB_k
  float* Bm    = (float*)(ws + 24 * MB);      // [24,40M), dead after gemm_big_k
  float* Ladj  = (float*)(ws + 40 * MB);      // over ea (dead after fill_k); alive to inv polish
  float* Gs    = (float*)(ws + 41 * MB);      // over eb (dead after fill_k); stage D
  int*   ea     = (int*)(ws + 40 * MB);       // dead after fill_k
  int*   eb     = (int*)(ws + 41 * MB);       // dead after fill_k
  float* ew     = (float*)(ws + 42 * MB);     // dead after fill_k
  int*   adjj   = (int*)(ws + 43 * MB);       // 2 MB, dead after buildB_k
  float* adjw   = (float*)(ws + 45 * MB);     // 2 MB, dead after buildB_k
  int*   cnt    = (int*)(ws + 47 * MB);
  int*   rowptr = (int*)(ws + 47 * MB + 64 * 1024);
  int*   cursor = (int*)(ws + 47 * MB + 128 * 1024);
  float* scal   = (float*)(ws + 47 * MB + 256 * 1024);
  float* SL[11];
  for (int i = 0; i < 11; ++i) SL[i] = (float*)(ws + (size_t)i * SLOT);
  float *Xa = SL[0], *Ra = SL[1], *Ya = SL[2], *Za = SL[3];
  float *Xb = SL[4], *Rb = SL[5], *Yb = SL[6], *Zb = SL[7];
  float *Pm = SL[8], *S0h = SL[9], *TMP = SL[10];

  hipMemsetAsync(bitmap, 0, (size_t)VN * VN / 8, stream);
  hipMemsetAsync(cnt, 0, (size_t)VN * 4, stream);
  hipMemsetAsync(scal, 0, 64 * 4, stream);

  // stage A: graph construction -> L_adj (fp32, PSD-safe)
  transpose_k<<<dim3(VN / 32, KD / 32), 256, 0, stream>>>(pmat, pmatT);
  count_k<<<EN / 16, 256, 0, stream>>>(x, ei, ea, eb, ew, cnt, bitmap);
  scan_k<<<1, 1024, 0, stream>>>(cnt, rowptr, cursor);
  fill_k<<<EN / 256, 256, 0, stream>>>(ea, eb, ew, cursor, adjj, adjw);
  buildB_k<<<VN, 512, 0, stream>>>(pmatT, rowptr, adjj, adjw, Bm);
  setid_const_k<<<KK / 256, 256, 0, stream>>>(Ladj, 1e-5f);
  gemm_big_k<<<dim3(8, 8, 8), 256, 0, stream>>>(pmat, Bm, Ladj);

  // stage B/C prep, merged: both sumsq, both derives, scale+setid pairs
  sumsq2_k<<<dim3(256, 1, 2), 256, 0, stream>>>(Ladj, &scal[S_SS_LADJ], S0, &scal[S_SS_S0]);
  derive2_k<<<1, 2, 0, stream>>>(scal);
  initinv_split_k<<<KK / 256, 256, 0, stream>>>(Ladj, &scal[S_INV_C1], Xa, Ra);
  prep2_k<<<dim3(KK / 256, 1, 2), 256, 0, stream>>>(S0, &scal[S_INV_C0], Ya, Za);

  // MFMA: 12 packed rounds (inv + sqrtS0), then 3 inv-only rounds (inv total 15)
  // sqrtS0: 12 + 1 fp32 polish = 2^13; a_min(S0) = 0.1/||S0||_F ~ 2.6e-3 -> converged.
  for (int r = 0; r < 12; ++r) {
    bc3_k<<<dim3(8, 8, 3), 256, 0, stream>>>(Za, Ya, Pm, Xa, Ra, Xb, Rb);
    yz2_k<<<dim3(8, 8, 2), 256, 0, stream>>>(Ya, Za, Pm, Yb, Zb);
    float* t = Xa; Xa = Xb; Xb = t;
    t = Ra; Ra = Rb; Rb = t;
    t = Ya; Ya = Yb; Yb = t;
    t = Za; Za = Zb; Zb = t;
  }
  for (int r = 0; r < 3; ++r) {
    inv2_k<<<dim3(8, 8, 2), 256, 0, stream>>>(Xa, Ra, Xb, Rb);
    float* t = Xa; Xa = Xb; Xb = t;
    t = Ra; Ra = Rb; Rb = t;
  }

  // packed polish L1: {U32 = Ladj@Xa} || {Pm = Za@Ya}
  float* U32  = Xb;
  float* Xfin = Rb;
  gemm_dual32<<<dim3(16, 16, 2), 256, 0, stream>>>(Ladj, Xa, nullptr, U32, 1.0f, 0.0f,
                                                   Za, Ya, nullptr, Pm, 1.0f, 0.0f);
  // packed polish L2: {Xfin = 2Xa - Xa@U32} || {Yb = 1.5Ya - 0.5 Ya@Pm}
  gemm_dual32<<<dim3(16, 16, 2), 256, 0, stream>>>(Xa, U32, Xa, Xfin, -1.0f, 2.0f,
                                                   Ya, Pm, Ya, Yb, -0.5f, 1.5f);
  trace2_k<<<dim3(1, 1, 2), 512, 0, stream>>>(Xfin, &scal[S_TR_X], S0, &scal[S_TR_S0]);
  scale32_k<<<KK / 256, 256, 0, stream>>>(Yb, &scal[S_QRT_C0], S0h);

  // stage D: G = S0h @ S1 @ S0h in fp32
  gemm_kk<<<dim3(16, 16), 256, 0, stream>>>(S0h, Xfin, nullptr, TMP, 1.0f, 0.0f);
  gemm_kk<<<dim3(16, 16), 256, 0, stream>>>(TMP, S0h, nullptr, Gs, 1.0f, 0.0f);
  symss_k<<<KK / 256, 256, 0, stream>>>(Gs, TMP, &scal[S_SS_G]);  // TMP = sym(G) + norm
  derive_k<<<1, 1, 0, stream>>>(&scal[S_SS_G], &scal[S_INV_CG], &scal[S_QRT_CG]);
  prep2_k<<<dim3(KK / 256, 1, 2), 256, 0, stream>>>(TMP, &scal[S_INV_CG], Ya, Za);
  // MFMA sqrt(G): 20 rounds (soft-mode tail needs every doubling — do not trim)
  for (int r = 0; r < 20; ++r) {
    pm1_k<<<dim3(8, 8, 1), 256, 0, stream>>>(Za, Ya, Pm);
    yz2_k<<<dim3(8, 8, 2), 256, 0, stream>>>(Ya, Za, Pm, Yb, Zb);
    float* t = Ya; Ya = Yb; Yb = t;
    t = Za; Za = Zb; Zb = t;
  }
  // sqrt(G) polish: two fp32 NS iterations
  gemm_kk<<<dim3(16, 16), 256, 0, stream>>>(Za, Ya, nullptr, Pm, 1.0f, 0.0f);
  gemm_dual32<<<dim3(16, 16, 2), 256, 0, stream>>>(Ya, Pm, Ya, Yb, -0.5f, 1.5f,
                                                   Pm, Za, Za, Zb, -0.5f, 1.5f);
  gemm_kk<<<dim3(16, 16), 256, 0, stream>>>(Zb, Yb, nullptr, Pm, 1.0f, 0.0f);
  gemm_kk<<<dim3(16, 16), 256, 0, stream>>>(Yb, Pm, Yb, S0h, -0.5f, 1.5f);  // S0h = Y_final
  trace_k<<<1, 512, 0, stream>>>(S0h, &scal[S_TR_YG]);

  final_k<<<1, 1, 0, stream>>>(scal, out);
}